// Round 5
// baseline (847.006 us; speedup 1.0000x reference)
//
#include <hip/hip_runtime.h>
#include <stdint.h>
#include <math.h>

typedef unsigned short u16;
typedef __attribute__((ext_vector_type(4))) float f32x4;
typedef __attribute__((ext_vector_type(8))) short s16x8;

#define U_N 8192
#define E_N 200000
#define M_PAD 200192   // 782 * 256
#define D_N 768
#define DE_N 50
#define KP_E 832
#define NT_E 26        // 832 / 32
#define BN_EPS 1e-5f

__device__ __forceinline__ u16 f2bf(float f) {
  union { float f; unsigned u; } v; v.f = f;
  return (u16)((v.u + 0x7fffu + ((v.u >> 16) & 1u)) >> 16);
}
__device__ __forceinline__ float bf2f(u16 v) {
  union { unsigned u; float f; } x; x.u = ((unsigned)v) << 16; return x.f;
}
__device__ __forceinline__ void gload16(const void* g, void* l) {
  __builtin_amdgcn_global_load_lds((const __attribute__((address_space(1))) void*)g,
                                   (__attribute__((address_space(3))) void*)l, 16, 0, 0);
}

// ---------------- searchsorted (left) ----------------
__global__ void k_localidx(const int* __restrict__ uniq, const int* __restrict__ src,
                           int* __restrict__ lidx) {
  int e = blockIdx.x * 256 + threadIdx.x;
  if (e >= E_N) return;
  int v = src[e];
  int lo = 0, hi = U_N;
  while (lo < hi) { int mid = (lo + hi) >> 1; if (uniq[mid] < v) lo = mid + 1; else hi = mid; }
  lidx[e] = lo;
}

// ---------------- counting sort: hist / scan / scatter ----------------
__global__ void k_hist(const int* __restrict__ lidx, int* __restrict__ counts) {
  int e = blockIdx.x * 256 + threadIdx.x;
  if (e < E_N) atomicAdd(&counts[lidx[e]], 1);
}

__global__ void k_scan(const int* __restrict__ counts, int* __restrict__ starts) {
  __shared__ int part[1024];
  const int t = threadIdx.x;
  const int base = t * 8;
  int loc[8]; int s = 0;
#pragma unroll
  for (int i = 0; i < 8; i++) { loc[i] = s; s += counts[base + i]; }
  part[t] = s; __syncthreads();
  for (int off = 1; off < 1024; off <<= 1) {
    int v = (t >= off) ? part[t - off] : 0;
    __syncthreads();
    part[t] += v;
    __syncthreads();
  }
  const int pre = (t == 0) ? 0 : part[t - 1];
#pragma unroll
  for (int i = 0; i < 8; i++) starts[base + i] = pre + loc[i];
  if (t == 1023) starts[8192] = pre + s;
}

__global__ void k_scatter(const int* __restrict__ lidx, const int* __restrict__ starts,
                          int* __restrict__ cursor, int* __restrict__ eord) {
  int e = blockIdx.x * 256 + threadIdx.x;
  if (e >= E_N) return;
  int u = lidx[e];
  int pos = atomicAdd(&cursor[u], 1);
  eord[starts[u] + pos] = e;
}

// ------- pack A in SORTED edge order: Abf[pos] = bf16(concat(tgt[eord[pos]], edg[eord[pos]], 0)) -------
__global__ void k_pack(const float* __restrict__ tgt, const float* __restrict__ edg,
                       const int* __restrict__ eord, u16* __restrict__ Abf) {
  const long long g = (long long)blockIdx.x * 256 + threadIdx.x;
  if (g >= (long long)E_N * 104) return;
  const int pos = (int)(g / 104), seg = (int)(g % 104);
  const int e = eord[pos];
  const int c0 = seg * 8;
  s16x8 v = {};
  if (c0 + 8 <= D_N) {
    const f32x4 f0 = *(const f32x4*)(tgt + (size_t)e * D_N + c0);
    const f32x4 f1 = *(const f32x4*)(tgt + (size_t)e * D_N + c0 + 4);
#pragma unroll
    for (int z = 0; z < 4; z++) { v[z] = (short)f2bf(f0[z]); v[4 + z] = (short)f2bf(f1[z]); }
  } else {
#pragma unroll
    for (int z = 0; z < 8; z++) {
      const int kk = c0 + z - D_N;
      v[z] = (short)f2bf(kk < DE_N ? edg[(size_t)e * DE_N + kk] : 0.f);
    }
  }
  *(s16x8*)&Abf[(size_t)pos * KP_E + c0] = v;
}

// ---------------- weight conversions ----------------
__global__ void k_conv_wedge(const float* __restrict__ W, u16* __restrict__ Wb) {
  int i = blockIdx.x * 256 + threadIdx.x;
  if (i >= D_N * KP_E) return;
  int n = i / KP_E, k = i % KP_E;
  float f = (k < D_N + DE_N) ? W[n * (D_N + DE_N) + k] : 0.f;
  Wb[i] = f2bf(f);
}

__global__ void k_conv_w(const float* __restrict__ W, u16* __restrict__ Wb, int count) {
  int i = blockIdx.x * 256 + threadIdx.x;
  if (i < count) Wb[i] = f2bf(W[i]);
}

// ====== edge GEMM v5: 256x256, BK=32, ring-4, software-pipelined frags + counted lgkm ======
// Steady iter t (buf c=t&3):
//   bar#1; STAGE(t+3); lgkmcnt(0)[lo(t),B(t)]; issue hi(t) reads; MFMA lo (overlaps hi reads);
//   vmcnt(8)[tile t+1 landed]; bar#2; issue lo(t+1)+B(t+1) reads (buf c+1);
//   lgkmcnt(8)[waits hi(t) only]; MFMA hi (overlaps next-tile reads).
__global__ __launch_bounds__(512, 2)
void gemm_edge5(const u16* __restrict__ Abf, const u16* __restrict__ Wb,
                const float* __restrict__ bias, u16* __restrict__ msgs) {
  __shared__ u16 As[4][256 * 32];
  __shared__ u16 Bs[4][256 * 32];

  // bijective XCD swizzle, nwg = 2346 = 8*293 + 2
  const int orig = blockIdx.x;
  const int xcd = orig & 7, i8 = orig >> 3;
  const int wgid = (xcd < 2 ? xcd * 294 : 588 + (xcd - 2) * 293) + i8;
  const int bm = (wgid / 3) * 256;
  const int bn = (wgid % 3) * 256;

  const int tid = threadIdx.x;
  const int w = tid >> 6, lane = tid & 63;
  const int wm = w >> 2, wn = w & 3;          // wave tile: rows wm*128, cols wn*64
  const int rl = lane & 15, K16 = lane >> 4;
  const int sws = ((K16 ^ ((rl >> 1) & 3)) << 3);
  const int srow = lane >> 2;
  const int sslot = lane & 3;
  const int sg = sslot ^ ((srow >> 1) & 3);

  const int arow = wm * 128 + rl;
  const int brow = wn * 64 + rl;

  f32x4 acc[8][4] = {};
  s16x8 fA0[4], fA1[4], fBa[4], fBb[4];

#define STAGE(T)                                                                        \
  {                                                                                     \
    const int b_ = (T) & 3;                                                             \
    const int k0_ = (T) * 32;                                                           \
    _Pragma("unroll")                                                                   \
    for (int q_ = 0; q_ < 2; ++q_) {                                                    \
      const int c_ = w * 2 + q_;                                                        \
      const int r_ = c_ * 16 + srow;                                                    \
      gload16(Abf + (size_t)(bm + r_) * KP_E + k0_ + sg * 8, &As[b_][c_ * 512]);        \
    }                                                                                   \
    _Pragma("unroll")                                                                   \
    for (int q_ = 0; q_ < 2; ++q_) {                                                    \
      const int c_ = w * 2 + q_;                                                        \
      const int r_ = c_ * 16 + srow;                                                    \
      gload16(Wb + (size_t)(bn + r_) * KP_E + k0_ + sg * 8, &Bs[b_][c_ * 512]);         \
    }                                                                                   \
  }

#define RD_LO(cb_, FB)                                                                  \
    _Pragma("unroll")                                                                   \
    for (int i_ = 0; i_ < 4; ++i_)                                                      \
      fA0[i_] = *(const s16x8*)&As[cb_][(arow + i_ * 16) * 32 + sws];                   \
    _Pragma("unroll")                                                                   \
    for (int j_ = 0; j_ < 4; ++j_)                                                      \
      FB[j_] = *(const s16x8*)&Bs[cb_][(brow + j_ * 16) * 32 + sws];

#define RD_HI(cb_)                                                                      \
    _Pragma("unroll")                                                                   \
    for (int i_ = 0; i_ < 4; ++i_)                                                      \
      fA1[i_] = *(const s16x8*)&As[cb_][(arow + (4 + i_) * 16) * 32 + sws];

#define MFMA16(AF, BF, base_)                                                           \
    __builtin_amdgcn_s_setprio(1);                                                      \
    _Pragma("unroll")                                                                   \
    for (int i_ = 0; i_ < 4; ++i_)                                                      \
      _Pragma("unroll")                                                                 \
      for (int j_ = 0; j_ < 4; ++j_)                                                    \
        acc[(base_) + i_][j_] = __builtin_amdgcn_mfma_f32_16x16x32_bf16(                \
            AF[i_], BF[j_], acc[(base_) + i_][j_], 0, 0, 0);                            \
    __builtin_amdgcn_s_setprio(0);

#define LGKM(n) asm volatile("s_waitcnt lgkmcnt(" #n ")" ::: "memory")
#define VMC(n)  asm volatile("s_waitcnt vmcnt(" #n ")" ::: "memory")
#define SCB()   __builtin_amdgcn_sched_barrier(0)
#define BAR()   __builtin_amdgcn_s_barrier()

#define ITER(T, FCUR, FNXT, STAGE_STMT, VM_STMT, NEXT_STMT, LGKM_STMT)                  \
  {                                                                                     \
    const int c_ = (T) & 3;                                                             \
    BAR();                                                                              \
    STAGE_STMT                                                                          \
    LGKM(0); SCB();                                                                     \
    RD_HI(c_)                                                                           \
    MFMA16(fA0, FCUR, 0)                                                                \
    VM_STMT                                                                             \
    BAR();                                                                              \
    NEXT_STMT                                                                           \
    LGKM_STMT; SCB();                                                                   \
    MFMA16(fA1, FCUR, 4)                                                                \
  }

  // prologue: stage tiles 0,1,2; land tile 0; preload lo(0)+B(0)
  STAGE(0)
  STAGE(1)
  STAGE(2)
  VMC(8);
  BAR();
  RD_LO(0, fBa)

  for (int tt = 0; tt < 11; ++tt) {
    const int t = tt * 2;                 // t = 0,2,...,20
    ITER(t,     fBa, fBb, STAGE(t + 3), VMC(8);, RD_LO((t + 1) & 3, fBb), LGKM(8))
    ITER(t + 1, fBb, fBa, STAGE(t + 4), VMC(8);, RD_LO((t + 2) & 3, fBa), LGKM(8))
  }
  // t=22 (buf 2): stage 25; in flight 23,24,25 -> vmcnt(8) lands 23
  ITER(22, fBa, fBb, STAGE(25), VMC(8);, RD_LO(3, fBb), LGKM(8))
  // t=23 (buf 3): in flight 24,25 -> vmcnt(4) lands 24
  ITER(23, fBb, fBa, , VMC(4);, RD_LO(0, fBa), LGKM(8))
  // t=24 (buf 0): in flight 25 -> vmcnt(0)
  ITER(24, fBa, fBb, , VMC(0);, RD_LO(1, fBb), LGKM(8))
  // t=25 (buf 1): drain
  ITER(25, fBb, fBa, , , , LGKM(0))

#undef STAGE
#undef RD_LO
#undef RD_HI
#undef MFMA16
#undef LGKM
#undef VMC
#undef SCB
#undef BAR
#undef ITER

  // epilogue: relu(acc + bias) -> bf16 msgs (sorted edge order)
  const int rq = (lane >> 4) * 4;
  const int cl = lane & 15;
#pragma unroll
  for (int j = 0; j < 4; ++j) {
    const int col = bn + wn * 64 + j * 16 + cl;
    const float bj = bias[col];
#pragma unroll
    for (int mf = 0; mf < 8; ++mf) {
      const int r0 = bm + wm * 128 + mf * 16 + rq;
#pragma unroll
      for (int q = 0; q < 4; ++q) {
        const float v = acc[mf][j][q] + bj;
        msgs[(size_t)(r0 + q) * D_N + col] = f2bf(v > 0.f ? v : 0.f);
      }
    }
  }
}

// ------- gather (sequential rows): h = (1+eps)*x + sum(msgs[starts[u]:starts[u+1]]) -> bf16 -------
__global__ __launch_bounds__(384)
void k_gather(const u16* __restrict__ msgs, const int* __restrict__ starts,
              const float* __restrict__ x, const float* __restrict__ epsp,
              u16* __restrict__ hbf) {
  const int u = blockIdx.x;
  const int c2 = threadIdx.x;
  const int s = starts[u], e = starts[u + 1];
  float a0 = 0.f, a1 = 0.f;
  for (int i = s; i < e; i++) {
    const unsigned v = *(const unsigned*)&msgs[(size_t)i * D_N + c2 * 2];
    a0 += bf2f((u16)(v & 0xffffu));
    a1 += bf2f((u16)(v >> 16));
  }
  const float ep = 1.f + epsp[0];
  const float2 xv = *(const float2*)&x[(size_t)u * D_N + c2 * 2];
  const unsigned o = ((unsigned)f2bf(ep * xv.y + a1) << 16) | (unsigned)f2bf(ep * xv.x + a0);
  *(unsigned*)&hbf[(size_t)u * D_N + c2 * 2] = o;
}

// ---------------- generic bf16 GEMM (m97 structure), C f32 [M][N], K%64==0 ----------------
__global__ __launch_bounds__(256)
void gemm_bf16_g(const u16* __restrict__ A, const u16* __restrict__ B,
                 float* __restrict__ C, int ntn, int K) {
  __shared__ u16 As[128 * 64];
  __shared__ u16 Bs[128 * 64];
  const int bm = (blockIdx.x / ntn) * 128;
  const int bn = (blockIdx.x % ntn) * 128;
  const int t = threadIdx.x;
  const int wave = t >> 6, lane = t & 63;
  const int wr = (wave & 1) * 64, wc = (wave >> 1) * 64;
  const int srow = lane >> 3, scol = (lane & 7) * 8;
  const int rl = lane & 15, kl = (lane >> 4) * 8;
  const int N = ntn * 128;
  f32x4 acc[4][4] = {};
  for (int k0 = 0; k0 < K; k0 += 64) {
#pragma unroll
    for (int q = 0; q < 4; q++) {
      const int c = wave * 4 + q;
      const int row = c * 8 + srow;
      gload16(A + (size_t)(bm + row) * K + k0 + scol, As + c * 512);
      gload16(B + (size_t)(bn + row) * K + k0 + scol, Bs + c * 512);
    }
    __syncthreads();
#pragma unroll
    for (int ks = 0; ks < 2; ks++) {
      s16x8 af[4], bfr[4];
#pragma unroll
      for (int i = 0; i < 4; i++) af[i] = *(const s16x8*)&As[(wr + i * 16 + rl) * 64 + ks * 32 + kl];
#pragma unroll
      for (int j = 0; j < 4; j++) bfr[j] = *(const s16x8*)&Bs[(wc + j * 16 + rl) * 64 + ks * 32 + kl];
#pragma unroll
      for (int i = 0; i < 4; i++)
#pragma unroll
        for (int j = 0; j < 4; j++)
          acc[i][j] = __builtin_amdgcn_mfma_f32_16x16x32_bf16(af[i], bfr[j], acc[i][j], 0, 0, 0);
    }
    __syncthreads();
  }
  const int cl = lane & 15, rq = (lane >> 4) * 4;
#pragma unroll
  for (int i = 0; i < 4; i++)
#pragma unroll
    for (int j = 0; j < 4; j++) {
      const int n = bn + wc + j * 16 + cl;
      const int r = bm + wr + i * 16 + rq;
#pragma unroll
      for (int q = 0; q < 4; q++)
        C[(size_t)(r + q) * N + n] = acc[i][j][q];
    }
}

// ---------------- BN ----------------
__global__ void k_bnstats(const float* __restrict__ h1, float* __restrict__ ssum,
                          float* __restrict__ ssq) {
  const int cchunk = blockIdx.x % 3;
  const int rchunk = blockIdx.x / 3;
  const int c = cchunk * 256 + threadIdx.x;
  const int r0 = rchunk * 256;
  float s = 0.f, s2 = 0.f;
  for (int r = r0; r < r0 + 256; r++) {
    float v = h1[(size_t)r * D_N + c];
    s += v; s2 += v * v;
  }
  atomicAdd(&ssum[c], s);
  atomicAdd(&ssq[c], s2);
}

__global__ void k_bnfinal(const float* __restrict__ ssum, const float* __restrict__ ssq,
                          const float* __restrict__ gamma, const float* __restrict__ beta,
                          float* __restrict__ scale, float* __restrict__ shift) {
  int c = blockIdx.x * 256 + threadIdx.x;
  if (c >= D_N) return;
  double mean = (double)ssum[c] / (double)U_N;
  double var = (double)ssq[c] / (double)U_N - mean * mean;
  float sc = (float)((double)gamma[c] / sqrt(var + (double)BN_EPS));
  scale[c] = sc;
  shift[c] = beta[c] - (float)mean * sc;
}

__global__ void k_bnapply(const float* __restrict__ h1, const float* __restrict__ scale,
                          const float* __restrict__ shift, u16* __restrict__ h2) {
  int i = blockIdx.x * 256 + threadIdx.x;
  if (i >= U_N * D_N) return;
  int c = i % D_N;
  float v = h1[i] * scale[c] + shift[c];
  h2[i] = f2bf(v > 0.f ? v : 0.f);
}

extern "C" void kernel_launch(void* const* d_in, const int* in_sizes, int n_in,
                              void* d_out, int out_size, void* d_ws, size_t ws_size,
                              hipStream_t stream) {
  const float* x     = (const float*)d_in[0];
  const int*   uniq  = (const int*)d_in[1];
  const int*   srcg  = (const int*)d_in[2];
  const float* tgt   = (const float*)d_in[3];
  const float* edg   = (const float*)d_in[4];
  const float* Wedge = (const float*)d_in[5];
  const float* bedge = (const float*)d_in[6];
  const float* W1    = (const float*)d_in[7];
  const float* W2    = (const float*)d_in[8];
  const float* gamma = (const float*)d_in[9];
  const float* beta  = (const float*)d_in[10];
  const float* epsp  = (const float*)d_in[11];
  float* out = (float*)d_out;
  char* ws = (char*)d_ws;

  u16*   Abf   = (u16*)  (ws + 0);            // 333,119,488
  u16*   msgs  = (u16*)  (ws + 333119488ull); // 307,494,912
  float* h1    = (float*)(ws + 640614400ull); // 25,165,824
  u16*   hbf   = (u16*)  (ws + 665780224ull); // 12,582,912
  u16*   h2b   = (u16*)  (ws + 678363136ull); // 12,582,912
  u16*   web   = (u16*)  (ws + 690946048ull); // 1,277,952
  u16*   w1b   = (u16*)  (ws + 692224000ull); // 1,179,648
  u16*   w2b   = (u16*)  (ws + 693403648ull); // 1,179,648
  int*   lidx  = (int*)  (ws + 694583296ull); // 800,000
  int*   eord  = (int*)  (ws + 695383296ull); // 800,000
  int*   counts= (int*)  (ws + 696183296ull); // 32,768
  int*   cursor= (int*)  (ws + 696216064ull); // 32,768
  int*   starts= (int*)  (ws + 696248832ull); // 32,776
  float* ssum  = (float*)(ws + 696281616ull); // 3,072
  float* ssq   = (float*)(ws + 696284688ull);
  float* scale = (float*)(ws + 696287760ull);
  float* shift = (float*)(ws + 696290832ull);

  hipMemsetAsync(counts, 0, 65536, stream);           // counts + cursor
  hipMemsetAsync(ssum, 0, 2 * D_N * 4, stream);       // ssum + ssq

  k_conv_wedge<<<(D_N * KP_E + 255) / 256, 256, 0, stream>>>(Wedge, web);
  k_conv_w<<<(D_N * D_N + 255) / 256, 256, 0, stream>>>(W1, w1b, D_N * D_N);
  k_conv_w<<<(D_N * D_N + 255) / 256, 256, 0, stream>>>(W2, w2b, D_N * D_N);

  k_localidx<<<(E_N + 255) / 256, 256, 0, stream>>>(uniq, srcg, lidx);
  k_hist<<<(E_N + 255) / 256, 256, 0, stream>>>(lidx, counts);
  k_scan<<<1, 1024, 0, stream>>>(counts, starts);
  k_scatter<<<(E_N + 255) / 256, 256, 0, stream>>>(lidx, starts, cursor, eord);

  // pack in sorted order (needs eord)
  k_pack<<<(int)(((long long)E_N * 104 + 255) / 256), 256, 0, stream>>>(tgt, edg, eord, Abf);

  gemm_edge5<<<782 * 3, 512, 0, stream>>>(Abf, web, bedge, msgs);

  k_gather<<<U_N, 384, 0, stream>>>(msgs, starts, x, epsp, hbf);

  gemm_bf16_g<<<(U_N / 128) * 6, 256, 0, stream>>>(hbf, w1b, h1, 6, D_N);

  k_bnstats<<<96, 256, 0, stream>>>(h1, ssum, ssq);
  k_bnfinal<<<3, 256, 0, stream>>>(ssum, ssq, gamma, beta, scale, shift);
  k_bnapply<<<(U_N * D_N + 255) / 256, 256, 0, stream>>>(h1, scale, shift, h2b);

  gemm_bf16_g<<<(U_N / 128) * 6, 256, 0, stream>>>(h2b, w2b, out, 6, D_N);
}

// Round 6
// 781.594 us; speedup vs baseline: 1.0837x; 1.0837x over previous
//
#include <hip/hip_runtime.h>
#include <stdint.h>
#include <math.h>

typedef unsigned short u16;
typedef __attribute__((ext_vector_type(4))) float f32x4;
typedef __attribute__((ext_vector_type(8))) short s16x8;

#define U_N 8192
#define E_N 200000
#define M_PAD 200192   // 782 * 256
#define D_N 768
#define DE_N 50
#define KP_E 832
#define NT_E 26        // 832 / 32
#define BN_EPS 1e-5f

__device__ __forceinline__ u16 f2bf(float f) {
  union { float f; unsigned u; } v; v.f = f;
  return (u16)((v.u + 0x7fffu + ((v.u >> 16) & 1u)) >> 16);
}
__device__ __forceinline__ float bf2f(u16 v) {
  union { unsigned u; float f; } x; x.u = ((unsigned)v) << 16; return x.f;
}
__device__ __forceinline__ void gload16(const void* g, void* l) {
  __builtin_amdgcn_global_load_lds((const __attribute__((address_space(1))) void*)g,
                                   (__attribute__((address_space(3))) void*)l, 16, 0, 0);
}

// ---------------- searchsorted (left) ----------------
__global__ void k_localidx(const int* __restrict__ uniq, const int* __restrict__ src,
                           int* __restrict__ lidx) {
  int e = blockIdx.x * 256 + threadIdx.x;
  if (e >= E_N) return;
  int v = src[e];
  int lo = 0, hi = U_N;
  while (lo < hi) { int mid = (lo + hi) >> 1; if (uniq[mid] < v) lo = mid + 1; else hi = mid; }
  lidx[e] = lo;
}

// ---------------- counting sort: hist / scan / scatter ----------------
__global__ void k_hist(const int* __restrict__ lidx, int* __restrict__ counts) {
  int e = blockIdx.x * 256 + threadIdx.x;
  if (e < E_N) atomicAdd(&counts[lidx[e]], 1);
}

__global__ void k_scan(const int* __restrict__ counts, int* __restrict__ starts) {
  __shared__ int part[1024];
  const int t = threadIdx.x;
  const int base = t * 8;
  int loc[8]; int s = 0;
#pragma unroll
  for (int i = 0; i < 8; i++) { loc[i] = s; s += counts[base + i]; }
  part[t] = s; __syncthreads();
  for (int off = 1; off < 1024; off <<= 1) {
    int v = (t >= off) ? part[t - off] : 0;
    __syncthreads();
    part[t] += v;
    __syncthreads();
  }
  const int pre = (t == 0) ? 0 : part[t - 1];
#pragma unroll
  for (int i = 0; i < 8; i++) starts[base + i] = pre + loc[i];
  if (t == 1023) starts[8192] = pre + s;
}

// scatter + build sorted-row -> node map (nsort)
__global__ void k_scatter(const int* __restrict__ lidx, const int* __restrict__ starts,
                          int* __restrict__ cursor, int* __restrict__ eord,
                          int* __restrict__ nsort) {
  int e = blockIdx.x * 256 + threadIdx.x;
  if (e >= E_N) return;
  int u = lidx[e];
  int pos = atomicAdd(&cursor[u], 1);
  eord[starts[u] + pos] = e;
  nsort[starts[u] + pos] = u;
}

// ------- pack A in SORTED edge order: Abf[pos] = bf16(concat(tgt[eord[pos]], edg[eord[pos]], 0)) -------
__global__ void k_pack(const float* __restrict__ tgt, const float* __restrict__ edg,
                       const int* __restrict__ eord, u16* __restrict__ Abf) {
  const long long g = (long long)blockIdx.x * 256 + threadIdx.x;
  if (g >= (long long)E_N * 104) return;
  const int pos = (int)(g / 104), seg = (int)(g % 104);
  const int e = eord[pos];
  const int c0 = seg * 8;
  s16x8 v = {};
  if (c0 + 8 <= D_N) {
    const f32x4 f0 = *(const f32x4*)(tgt + (size_t)e * D_N + c0);
    const f32x4 f1 = *(const f32x4*)(tgt + (size_t)e * D_N + c0 + 4);
#pragma unroll
    for (int z = 0; z < 4; z++) { v[z] = (short)f2bf(f0[z]); v[4 + z] = (short)f2bf(f1[z]); }
  } else {
#pragma unroll
    for (int z = 0; z < 8; z++) {
      const int kk = c0 + z - D_N;
      v[z] = (short)f2bf(kk < DE_N ? edg[(size_t)e * DE_N + kk] : 0.f);
    }
  }
  *(s16x8*)&Abf[(size_t)pos * KP_E + c0] = v;
}

// ---------------- weight conversions ----------------
__global__ void k_conv_wedge(const float* __restrict__ W, u16* __restrict__ Wb) {
  int i = blockIdx.x * 256 + threadIdx.x;
  if (i >= D_N * KP_E) return;
  int n = i / KP_E, k = i % KP_E;
  float f = (k < D_N + DE_N) ? W[n * (D_N + DE_N) + k] : 0.f;
  Wb[i] = f2bf(f);
}

__global__ void k_conv_w(const float* __restrict__ W, u16* __restrict__ Wb, int count) {
  int i = blockIdx.x * 256 + threadIdx.x;
  if (i < count) Wb[i] = f2bf(W[i]);
}

// ====== edge GEMM v6: v5 core (256x256, BK=32, ring-4, pipelined frags) ======
// + FUSED segment-sum epilogue: relu tile -> LDS -> per-column segmented
//   reduction over sorted destination nodes -> sparse f32 atomics into agg.
__global__ __launch_bounds__(512, 2)
void gemm_edge6(const u16* __restrict__ Abf, const u16* __restrict__ Wb,
                const float* __restrict__ bias, const int* __restrict__ nsort,
                float* __restrict__ agg) {
  __shared__ u16 As[4][256 * 32];
  __shared__ u16 Bs[4][256 * 32];
  __shared__ int nseg[256];

  // bijective XCD swizzle, nwg = 2346 = 8*293 + 2
  const int orig = blockIdx.x;
  const int xcd = orig & 7, i8 = orig >> 3;
  const int wgid = (xcd < 2 ? xcd * 294 : 588 + (xcd - 2) * 293) + i8;
  const int bm = (wgid / 3) * 256;
  const int bn = (wgid % 3) * 256;

  const int tid = threadIdx.x;
  const int w = tid >> 6, lane = tid & 63;
  const int wm = w >> 2, wn = w & 3;          // wave tile: rows wm*128, cols wn*64
  const int rl = lane & 15, K16 = lane >> 4;
  const int sws = ((K16 ^ ((rl >> 1) & 3)) << 3);
  const int srow = lane >> 2;
  const int sslot = lane & 3;
  const int sg = sslot ^ ((srow >> 1) & 3);

  const int arow = wm * 128 + rl;
  const int brow = wn * 64 + rl;

  f32x4 acc[8][4] = {};
  s16x8 fA0[4], fA1[4], fBa[4], fBb[4];

#define STAGE(T)                                                                        \
  {                                                                                     \
    const int b_ = (T) & 3;                                                             \
    const int k0_ = (T) * 32;                                                           \
    _Pragma("unroll")                                                                   \
    for (int q_ = 0; q_ < 2; ++q_) {                                                    \
      const int c_ = w * 2 + q_;                                                        \
      const int r_ = c_ * 16 + srow;                                                    \
      gload16(Abf + (size_t)(bm + r_) * KP_E + k0_ + sg * 8, &As[b_][c_ * 512]);        \
    }                                                                                   \
    _Pragma("unroll")                                                                   \
    for (int q_ = 0; q_ < 2; ++q_) {                                                    \
      const int c_ = w * 2 + q_;                                                        \
      const int r_ = c_ * 16 + srow;                                                    \
      gload16(Wb + (size_t)(bn + r_) * KP_E + k0_ + sg * 8, &Bs[b_][c_ * 512]);         \
    }                                                                                   \
  }

#define RD_LO(cb_, FB)                                                                  \
    _Pragma("unroll")                                                                   \
    for (int i_ = 0; i_ < 4; ++i_)                                                      \
      fA0[i_] = *(const s16x8*)&As[cb_][(arow + i_ * 16) * 32 + sws];                   \
    _Pragma("unroll")                                                                   \
    for (int j_ = 0; j_ < 4; ++j_)                                                      \
      FB[j_] = *(const s16x8*)&Bs[cb_][(brow + j_ * 16) * 32 + sws];

#define RD_HI(cb_)                                                                      \
    _Pragma("unroll")                                                                   \
    for (int i_ = 0; i_ < 4; ++i_)                                                      \
      fA1[i_] = *(const s16x8*)&As[cb_][(arow + (4 + i_) * 16) * 32 + sws];

#define MFMA16(AF, BF, base_)                                                           \
    __builtin_amdgcn_s_setprio(1);                                                      \
    _Pragma("unroll")                                                                   \
    for (int i_ = 0; i_ < 4; ++i_)                                                      \
      _Pragma("unroll")                                                                 \
      for (int j_ = 0; j_ < 4; ++j_)                                                    \
        acc[(base_) + i_][j_] = __builtin_amdgcn_mfma_f32_16x16x32_bf16(                \
            AF[i_], BF[j_], acc[(base_) + i_][j_], 0, 0, 0);                            \
    __builtin_amdgcn_s_setprio(0);

#define LGKM(n) asm volatile("s_waitcnt lgkmcnt(" #n ")" ::: "memory")
#define VMC(n)  asm volatile("s_waitcnt vmcnt(" #n ")" ::: "memory")
#define SCB()   __builtin_amdgcn_sched_barrier(0)
#define BAR()   __builtin_amdgcn_s_barrier()

#define ITER(T, FCUR, FNXT, STAGE_STMT, VM_STMT, NEXT_STMT, LGKM_STMT)                  \
  {                                                                                     \
    const int c_ = (T) & 3;                                                             \
    BAR();                                                                              \
    STAGE_STMT                                                                          \
    LGKM(0); SCB();                                                                     \
    RD_HI(c_)                                                                           \
    MFMA16(fA0, FCUR, 0)                                                                \
    VM_STMT                                                                             \
    BAR();                                                                              \
    NEXT_STMT                                                                           \
    LGKM_STMT; SCB();                                                                   \
    MFMA16(fA1, FCUR, 4)                                                                \
  }

  // prologue: stage tiles 0,1,2; land tile 0; preload lo(0)+B(0)
  STAGE(0)
  STAGE(1)
  STAGE(2)
  VMC(8);
  BAR();
  RD_LO(0, fBa)

  for (int tt = 0; tt < 11; ++tt) {
    const int t = tt * 2;                 // t = 0,2,...,20
    ITER(t,     fBa, fBb, STAGE(t + 3), VMC(8);, RD_LO((t + 1) & 3, fBb), LGKM(8))
    ITER(t + 1, fBb, fBa, STAGE(t + 4), VMC(8);, RD_LO((t + 2) & 3, fBa), LGKM(8))
  }
  // t=22 (buf 2): stage 25; in flight 23,24,25 -> vmcnt(8) lands 23
  ITER(22, fBa, fBb, STAGE(25), VMC(8);, RD_LO(3, fBb), LGKM(8))
  // t=23 (buf 3): in flight 24,25 -> vmcnt(4) lands 24
  ITER(23, fBb, fBa, , VMC(4);, RD_LO(0, fBa), LGKM(8))
  // t=24 (buf 0): in flight 25 -> vmcnt(0)
  ITER(24, fBa, fBb, , VMC(0);, RD_LO(1, fBb), LGKM(8))
  // t=25 (buf 1): drain
  ITER(25, fBb, fBa, , , , LGKM(0))

#undef STAGE
#undef RD_LO
#undef RD_HI
#undef MFMA16
#undef ITER

  // ===== fused epilogue: relu(acc+bias) -> LDS tile -> segmented sum -> agg atomics =====
  BAR();  // all waves done with ring-buffer LDS (frags are in registers)

  u16* tileLds = (u16*)&As[0][0];   // reuse 128 KiB ring as [256][256] bf16
  const int rq = (lane >> 4) * 4;
  const int cl = lane & 15;
#pragma unroll
  for (int j = 0; j < 4; ++j) {
    const int col16 = wn * 64 + j * 16 + cl;
    const float bj = bias[bn + col16];
#pragma unroll
    for (int mf = 0; mf < 8; ++mf) {
      const int r0 = wm * 128 + mf * 16 + rq;
#pragma unroll
      for (int q = 0; q < 4; ++q) {
        const float v = acc[mf][q & 3][q] + 0.f;  // placeholder, replaced below
      }
    }
  }
  // (real write loop — kept separate from the dummy above for clarity)
#pragma unroll
  for (int j = 0; j < 4; ++j) {
    const int col16 = wn * 64 + j * 16 + cl;
    const float bj = bias[bn + col16];
#pragma unroll
    for (int mf = 0; mf < 8; ++mf) {
      const int r0 = wm * 128 + mf * 16 + rq;
#pragma unroll
      for (int q = 0; q < 4; ++q) {
        const float v = acc[mf][j][q] + bj;
        tileLds[(r0 + q) * 256 + col16] = f2bf(v > 0.f ? v : 0.f);
      }
    }
  }
  // node map for this tile's rows
  for (int i = tid; i < 256; i += 512) nseg[i] = nsort[bm + i];
  __syncthreads();

  // threads 0..255: col=tid, rows 0..127; threads 256..511: col=tid-256, rows 128..255
  const int col = tid & 255;
  const int rbase = (tid >> 8) * 128;
  float s = 0.f;
  int cur = -1;
  for (int r = 0; r < 128; ++r) {
    const int nd = nseg[rbase + r];
    const float v = bf2f(tileLds[(rbase + r) * 256 + col]);
    if (nd != cur) {
      if (cur >= 0) atomicAdd(&agg[(size_t)cur * D_N + bn + col], s);
      s = 0.f;
      cur = nd;
    }
    if (nd >= 0) s += v;
  }
  if (cur >= 0) atomicAdd(&agg[(size_t)cur * D_N + bn + col], s);

#undef LGKM
#undef VMC
#undef SCB
#undef BAR
}

// ---------------- GIN combine: h = (1+eps)*x + agg -> bf16 ----------------
__global__ void k_build_h(const float* __restrict__ x, const float* __restrict__ agg,
                          const float* __restrict__ epsp, u16* __restrict__ hbf) {
  int i = blockIdx.x * 256 + threadIdx.x;
  if (i >= U_N * D_N) return;
  float h = (1.f + epsp[0]) * x[i] + agg[i];
  hbf[i] = f2bf(h);
}

// ---------------- generic bf16 GEMM (m97 structure), C f32 [M][N], K%64==0 ----------------
__global__ __launch_bounds__(256)
void gemm_bf16_g(const u16* __restrict__ A, const u16* __restrict__ B,
                 float* __restrict__ C, int ntn, int K) {
  __shared__ u16 As[128 * 64];
  __shared__ u16 Bs[128 * 64];
  const int bm = (blockIdx.x / ntn) * 128;
  const int bn = (blockIdx.x % ntn) * 128;
  const int t = threadIdx.x;
  const int wave = t >> 6, lane = t & 63;
  const int wr = (wave & 1) * 64, wc = (wave >> 1) * 64;
  const int srow = lane >> 3, scol = (lane & 7) * 8;
  const int rl = lane & 15, kl = (lane >> 4) * 8;
  const int N = ntn * 128;
  f32x4 acc[4][4] = {};
  for (int k0 = 0; k0 < K; k0 += 64) {
#pragma unroll
    for (int q = 0; q < 4; q++) {
      const int c = wave * 4 + q;
      const int row = c * 8 + srow;
      gload16(A + (size_t)(bm + row) * K + k0 + scol, As + c * 512);
      gload16(B + (size_t)(bn + row) * K + k0 + scol, Bs + c * 512);
    }
    __syncthreads();
#pragma unroll
    for (int ks = 0; ks < 2; ks++) {
      s16x8 af[4], bfr[4];
#pragma unroll
      for (int i = 0; i < 4; i++) af[i] = *(const s16x8*)&As[(wr + i * 16 + rl) * 64 + ks * 32 + kl];
#pragma unroll
      for (int j = 0; j < 4; j++) bfr[j] = *(const s16x8*)&Bs[(wc + j * 16 + rl) * 64 + ks * 32 + kl];
#pragma unroll
      for (int i = 0; i < 4; i++)
#pragma unroll
        for (int j = 0; j < 4; j++)
          acc[i][j] = __builtin_amdgcn_mfma_f32_16x16x32_bf16(af[i], bfr[j], acc[i][j], 0, 0, 0);
    }
    __syncthreads();
  }
  const int cl = lane & 15, rq = (lane >> 4) * 4;
#pragma unroll
  for (int i = 0; i < 4; i++)
#pragma unroll
    for (int j = 0; j < 4; j++) {
      const int n = bn + wc + j * 16 + cl;
      const int r = bm + wr + i * 16 + rq;
#pragma unroll
      for (int q = 0; q < 4; q++)
        C[(size_t)(r + q) * N + n] = acc[i][j][q];
    }
}

// ---------------- BN ----------------
__global__ void k_bnstats(const float* __restrict__ h1, float* __restrict__ ssum,
                          float* __restrict__ ssq) {
  const int cchunk = blockIdx.x % 3;
  const int rchunk = blockIdx.x / 3;
  const int c = cchunk * 256 + threadIdx.x;
  const int r0 = rchunk * 256;
  float s = 0.f, s2 = 0.f;
  for (int r = r0; r < r0 + 256; r++) {
    float v = h1[(size_t)r * D_N + c];
    s += v; s2 += v * v;
  }
  atomicAdd(&ssum[c], s);
  atomicAdd(&ssq[c], s2);
}

__global__ void k_bnfinal(const float* __restrict__ ssum, const float* __restrict__ ssq,
                          const float* __restrict__ gamma, const float* __restrict__ beta,
                          float* __restrict__ scale, float* __restrict__ shift) {
  int c = blockIdx.x * 256 + threadIdx.x;
  if (c >= D_N) return;
  double mean = (double)ssum[c] / (double)U_N;
  double var = (double)ssq[c] / (double)U_N - mean * mean;
  float sc = (float)((double)gamma[c] / sqrt(var + (double)BN_EPS));
  scale[c] = sc;
  shift[c] = beta[c] - (float)mean * sc;
}

__global__ void k_bnapply(const float* __restrict__ h1, const float* __restrict__ scale,
                          const float* __restrict__ shift, u16* __restrict__ h2) {
  int i = blockIdx.x * 256 + threadIdx.x;
  if (i >= U_N * D_N) return;
  int c = i % D_N;
  float v = h1[i] * scale[c] + shift[c];
  h2[i] = f2bf(v > 0.f ? v : 0.f);
}

extern "C" void kernel_launch(void* const* d_in, const int* in_sizes, int n_in,
                              void* d_out, int out_size, void* d_ws, size_t ws_size,
                              hipStream_t stream) {
  const float* x     = (const float*)d_in[0];
  const int*   uniq  = (const int*)d_in[1];
  const int*   srcg  = (const int*)d_in[2];
  const float* tgt   = (const float*)d_in[3];
  const float* edg   = (const float*)d_in[4];
  const float* Wedge = (const float*)d_in[5];
  const float* bedge = (const float*)d_in[6];
  const float* W1    = (const float*)d_in[7];
  const float* W2    = (const float*)d_in[8];
  const float* gamma = (const float*)d_in[9];
  const float* beta  = (const float*)d_in[10];
  const float* epsp  = (const float*)d_in[11];
  float* out = (float*)d_out;
  char* ws = (char*)d_ws;

  u16*   Abf   = (u16*)  (ws + 0);            // 333,119,488
  float* agg   = (float*)(ws + 333119488ull); // 25,165,824
  float* h1    = (float*)(ws + 358285312ull); // 25,165,824
  u16*   hbf   = (u16*)  (ws + 383451136ull); // 12,582,912
  u16*   h2b   = (u16*)  (ws + 396034048ull); // 12,582,912
  u16*   web   = (u16*)  (ws + 408616960ull); // 1,277,952
  u16*   w1b   = (u16*)  (ws + 409894912ull); // 1,179,648
  u16*   w2b   = (u16*)  (ws + 411074560ull); // 1,179,648
  int*   lidx  = (int*)  (ws + 412254208ull); // 800,000
  int*   eord  = (int*)  (ws + 413054208ull); // 800,000
  int*   nsort = (int*)  (ws + 413854208ull); // 800,772 -> 800,776
  int*   counts= (int*)  (ws + 414654984ull); // 32,768
  int*   cursor= (int*)  (ws + 414687752ull); // 32,768
  int*   starts= (int*)  (ws + 414720520ull); // 32,776
  float* ssum  = (float*)(ws + 414753296ull); // 3,072
  float* ssq   = (float*)(ws + 414756368ull);
  float* scale = (float*)(ws + 414759440ull);
  float* shift = (float*)(ws + 414762512ull);

  hipMemsetAsync(counts, 0, 65536, stream);                 // counts + cursor
  hipMemsetAsync(ssum, 0, 2 * D_N * 4, stream);             // ssum + ssq
  hipMemsetAsync(agg, 0, (size_t)U_N * D_N * 4, stream);    // agg zeros
  hipMemsetAsync(nsort + E_N, 0xFF, (M_PAD + 1 - E_N) * 4, stream);  // pad rows -> -1

  k_conv_wedge<<<(D_N * KP_E + 255) / 256, 256, 0, stream>>>(Wedge, web);
  k_conv_w<<<(D_N * D_N + 255) / 256, 256, 0, stream>>>(W1, w1b, D_N * D_N);
  k_conv_w<<<(D_N * D_N + 255) / 256, 256, 0, stream>>>(W2, w2b, D_N * D_N);

  k_localidx<<<(E_N + 255) / 256, 256, 0, stream>>>(uniq, srcg, lidx);
  k_hist<<<(E_N + 255) / 256, 256, 0, stream>>>(lidx, counts);
  k_scan<<<1, 1024, 0, stream>>>(counts, starts);
  k_scatter<<<(E_N + 255) / 256, 256, 0, stream>>>(lidx, starts, cursor, eord, nsort);

  // pack in sorted order (needs eord)
  k_pack<<<(int)(((long long)E_N * 104 + 255) / 256), 256, 0, stream>>>(tgt, edg, eord, Abf);

  // fused GEMM + segment-sum
  gemm_edge6<<<782 * 3, 512, 0, stream>>>(Abf, web, bedge, nsort, agg);

  k_build_h<<<(U_N * D_N + 255) / 256, 256, 0, stream>>>(x, agg, epsp, hbf);

  gemm_bf16_g<<<(U_N / 128) * 6, 256, 0, stream>>>(hbf, w1b, h1, 6, D_N);

  k_bnstats<<<96, 256, 0, stream>>>(h1, ssum, ssq);
  k_bnfinal<<<3, 256, 0, stream>>>(ssum, ssq, gamma, beta, scale, shift);
  k_bnapply<<<(U_N * D_N + 255) / 256, 256, 0, stream>>>(h1, scale, shift, h2b);

  gemm_bf16_g<<<(U_N / 128) * 6, 256, 0, stream>>>(h2b, w2b, out, 6, D_N);
}

// Round 7
// 583.571 us; speedup vs baseline: 1.4514x; 1.3393x over previous
//
#include <hip/hip_runtime.h>
#include <stdint.h>
#include <math.h>

typedef unsigned short u16;
typedef __attribute__((ext_vector_type(4))) float f32x4;
typedef __attribute__((ext_vector_type(8))) short s16x8;
typedef __attribute__((ext_vector_type(4))) int i32x4;

#define U_N 8192
#define E_N 200000
#define M_PAD 200192   // 782 * 256
#define D_N 768
#define DE_N 50
#define KP_E 832       // 13 * 64
#define NTI 13         // K-tiles of 64
#define BN_EPS 1e-5f

__device__ __forceinline__ u16 f2bf(float f) {
  union { float f; unsigned u; } v; v.f = f;
  return (u16)((v.u + 0x7fffu + ((v.u >> 16) & 1u)) >> 16);
}
__device__ __forceinline__ float bf2f(u16 v) {
  union { unsigned u; float f; } x; x.u = ((unsigned)v) << 16; return x.f;
}
__device__ __forceinline__ void gload16(const void* g, void* l) {
  __builtin_amdgcn_global_load_lds((const __attribute__((address_space(1))) void*)g,
                                   (__attribute__((address_space(3))) void*)l, 16, 0, 0);
}

// ---------------- searchsorted (left) ----------------
__global__ void k_localidx(const int* __restrict__ uniq, const int* __restrict__ src,
                           int* __restrict__ lidx) {
  int e = blockIdx.x * 256 + threadIdx.x;
  if (e >= E_N) return;
  int v = src[e];
  int lo = 0, hi = U_N;
  while (lo < hi) { int mid = (lo + hi) >> 1; if (uniq[mid] < v) lo = mid + 1; else hi = mid; }
  lidx[e] = lo;
}

// ---------------- counting sort: hist / scan / scatter ----------------
__global__ void k_hist(const int* __restrict__ lidx, int* __restrict__ counts) {
  int e = blockIdx.x * 256 + threadIdx.x;
  if (e < E_N) atomicAdd(&counts[lidx[e]], 1);
}

__global__ void k_scan(const int* __restrict__ counts, int* __restrict__ starts) {
  __shared__ int part[1024];
  const int t = threadIdx.x;
  const int base = t * 8;
  int loc[8]; int s = 0;
#pragma unroll
  for (int i = 0; i < 8; i++) { loc[i] = s; s += counts[base + i]; }
  part[t] = s; __syncthreads();
  for (int off = 1; off < 1024; off <<= 1) {
    int v = (t >= off) ? part[t - off] : 0;
    __syncthreads();
    part[t] += v;
    __syncthreads();
  }
  const int pre = (t == 0) ? 0 : part[t - 1];
#pragma unroll
  for (int i = 0; i < 8; i++) starts[base + i] = pre + loc[i];
  if (t == 1023) starts[8192] = pre + s;
}

__global__ void k_scatter(const int* __restrict__ lidx, const int* __restrict__ starts,
                          int* __restrict__ cursor, int* __restrict__ eord,
                          int* __restrict__ nsort) {
  int e = blockIdx.x * 256 + threadIdx.x;
  if (e >= E_N) return;
  int u = lidx[e];
  int pos = atomicAdd(&cursor[u], 1);
  eord[starts[u] + pos] = e;
  nsort[starts[u] + pos] = u;
}

// ------- pack+quantize A (sorted order): Aq[pos][k] = int8, per-row amax scale -------
__global__ __launch_bounds__(256)
void k_pack_q8(const float* __restrict__ tgt, const float* __restrict__ edg,
               const int* __restrict__ eord, char* __restrict__ Aq,
               float* __restrict__ sA) {
  const int row = blockIdx.x * 4 + (threadIdx.x >> 6);
  const int lane = threadIdx.x & 63;
  if (row >= E_N) return;
  const int e = eord[row];
  const int k0 = lane * 16;
  float v[16];
#pragma unroll
  for (int z = 0; z < 16; z++) v[z] = 0.f;
  if (k0 < D_N) {
    const f32x4* p = (const f32x4*)(tgt + (size_t)e * D_N + k0);
#pragma unroll
    for (int zz = 0; zz < 4; zz++) {
      const f32x4 f = p[zz];
#pragma unroll
      for (int b = 0; b < 4; b++) v[zz * 4 + b] = f[b];
    }
  } else if (k0 < KP_E) {
#pragma unroll
    for (int z = 0; z < 16; z++) {
      const int kk = k0 + z - D_N;
      v[z] = (kk < DE_N) ? edg[(size_t)e * DE_N + kk] : 0.f;
    }
  }
  float am = 0.f;
#pragma unroll
  for (int z = 0; z < 16; z++) am = fmaxf(am, fabsf(v[z]));
#pragma unroll
  for (int off = 32; off > 0; off >>= 1) am = fmaxf(am, __shfl_xor(am, off));
  am = fmaxf(am, 1e-8f);
  const float inv = 127.f / am;
  if (lane == 0) sA[row] = am / 127.f;
  if (k0 < KP_E) {
    int wq[4];
#pragma unroll
    for (int zz = 0; zz < 4; zz++) {
      int b0 = (int)rintf(fminf(fmaxf(v[zz*4+0] * inv, -127.f), 127.f));
      int b1 = (int)rintf(fminf(fmaxf(v[zz*4+1] * inv, -127.f), 127.f));
      int b2 = (int)rintf(fminf(fmaxf(v[zz*4+2] * inv, -127.f), 127.f));
      int b3 = (int)rintf(fminf(fmaxf(v[zz*4+3] * inv, -127.f), 127.f));
      wq[zz] = (b0 & 255) | ((b1 & 255) << 8) | ((b2 & 255) << 16) | (b3 << 24);
    }
    i32x4 out = {wq[0], wq[1], wq[2], wq[3]};
    *(i32x4*)(Aq + (size_t)row * KP_E + k0) = out;
  }
}

// ------- quantize W_edge rows (length 818 -> 832 pad), per-row amax -------
__global__ __launch_bounds__(256)
void k_convw_q8(const float* __restrict__ W, char* __restrict__ Wq,
                float* __restrict__ sW) {
  const int row = blockIdx.x * 4 + (threadIdx.x >> 6);
  const int lane = threadIdx.x & 63;
  if (row >= D_N) return;
  const int k0 = lane * 16;
  float v[16];
#pragma unroll
  for (int z = 0; z < 16; z++) v[z] = 0.f;
  if (k0 < KP_E) {
#pragma unroll
    for (int z = 0; z < 16; z++) {
      const int kk = k0 + z;
      v[z] = (kk < D_N + DE_N) ? W[(size_t)row * (D_N + DE_N) + kk] : 0.f;
    }
  }
  float am = 0.f;
#pragma unroll
  for (int z = 0; z < 16; z++) am = fmaxf(am, fabsf(v[z]));
#pragma unroll
  for (int off = 32; off > 0; off >>= 1) am = fmaxf(am, __shfl_xor(am, off));
  am = fmaxf(am, 1e-8f);
  const float inv = 127.f / am;
  if (lane == 0) sW[row] = am / 127.f;
  if (k0 < KP_E) {
    int wq[4];
#pragma unroll
    for (int zz = 0; zz < 4; zz++) {
      int b0 = (int)rintf(fminf(fmaxf(v[zz*4+0] * inv, -127.f), 127.f));
      int b1 = (int)rintf(fminf(fmaxf(v[zz*4+1] * inv, -127.f), 127.f));
      int b2 = (int)rintf(fminf(fmaxf(v[zz*4+2] * inv, -127.f), 127.f));
      int b3 = (int)rintf(fminf(fmaxf(v[zz*4+3] * inv, -127.f), 127.f));
      wq[zz] = (b0 & 255) | ((b1 & 255) << 8) | ((b2 & 255) << 16) | (b3 << 24);
    }
    i32x4 out = {wq[0], wq[1], wq[2], wq[3]};
    *(i32x4*)(Wq + (size_t)row * KP_E + k0) = out;
  }
}

// ---------------- weight conversion (bf16, for W1/W2) ----------------
__global__ void k_conv_w(const float* __restrict__ W, u16* __restrict__ Wb, int count) {
  int i = blockIdx.x * 256 + threadIdx.x;
  if (i < count) Wb[i] = f2bf(W[i]);
}

// ====== edge GEMM v7: int8 (mfma_i32_16x16x64_i8), 256x256, BK=64, ring-4 ======
// + fused dequant + segment-sum epilogue (sorted destinations, sparse f32 atomics).
__global__ __launch_bounds__(512)
void gemm_edge7(const char* __restrict__ Aq, const char* __restrict__ Wq,
                const float* __restrict__ sA, const float* __restrict__ sW,
                const float* __restrict__ bias, const int* __restrict__ nsort,
                float* __restrict__ agg) {
  // LDS: ring A = 4x16KB at 0, ring B = 4x16KB at 65536 (total 128KB).
  // Epilogue reuses [0,137216) as u16 tile[256][268]; nseg at 137216; sAl at 138240.
  __shared__ char lds[139264];

  // bijective XCD swizzle, nwg = 2346 = 8*293 + 2
  const int orig = blockIdx.x;
  const int xcd = orig & 7, i8_ = orig >> 3;
  const int wgid = (xcd < 2 ? xcd * 294 : 588 + (xcd - 2) * 293) + i8_;
  const int bm = (wgid / 3) * 256;
  const int bn = (wgid % 3) * 256;

  const int tid = threadIdx.x;
  const int w = tid >> 6, lane = tid & 63;
  const int wm = w >> 2, wn = w & 3;          // wave tile: rows wm*128, cols wn*64
  const int rl = lane & 15, K16 = lane >> 4;
  const int sws16 = (K16 ^ ((rl >> 1) & 3)) * 16;   // swizzled 16B slot (bytes)
  const int srow = lane >> 2;                 // staging: 16 rows x 4 slots
  const int sslot = lane & 3;
  const int sg = sslot ^ ((srow >> 1) & 3);

  i32x4 acc[8][4] = {};

#define STAGE(T)                                                                        \
  {                                                                                     \
    const int b_ = (T) & 3;                                                             \
    const int k0_ = (T) * 64;                                                           \
    _Pragma("unroll")                                                                   \
    for (int q_ = 0; q_ < 2; ++q_) {                                                    \
      const int c_ = w * 2 + q_;                                                        \
      const int r_ = c_ * 16 + srow;                                                    \
      gload16(Aq + (size_t)(bm + r_) * KP_E + k0_ + sg * 16, lds + b_ * 16384 + c_ * 1024); \
    }                                                                                   \
    _Pragma("unroll")                                                                   \
    for (int q_ = 0; q_ < 2; ++q_) {                                                    \
      const int c_ = w * 2 + q_;                                                        \
      const int r_ = c_ * 16 + srow;                                                    \
      gload16(Wq + (size_t)(bn + r_) * KP_E + k0_ + sg * 16, lds + 65536 + b_ * 16384 + c_ * 1024); \
    }                                                                                   \
  }

#define COMPUTE(BB)                                                                     \
  {                                                                                     \
    const char* Ab = lds + (BB) * 16384;                                                \
    const char* Bb = lds + 65536 + (BB) * 16384;                                        \
    i32x4 bfr[4], af[4];                                                                \
    _Pragma("unroll")                                                                   \
    for (int j_ = 0; j_ < 4; ++j_)                                                      \
      bfr[j_] = *(const i32x4*)(Bb + (wn * 64 + j_ * 16 + rl) * 64 + sws16);            \
    _Pragma("unroll")                                                                   \
    for (int i_ = 0; i_ < 4; ++i_)                                                      \
      af[i_] = *(const i32x4*)(Ab + (wm * 128 + i_ * 16 + rl) * 64 + sws16);            \
    __builtin_amdgcn_s_setprio(1);                                                      \
    _Pragma("unroll")                                                                   \
    for (int i_ = 0; i_ < 4; ++i_)                                                      \
      _Pragma("unroll")                                                                 \
      for (int j_ = 0; j_ < 4; ++j_)                                                    \
        acc[i_][j_] = __builtin_amdgcn_mfma_i32_16x16x64_i8(af[i_], bfr[j_],            \
                                                            acc[i_][j_], 0, 0, 0);     \
    __builtin_amdgcn_s_setprio(0);                                                      \
    _Pragma("unroll")                                                                   \
    for (int i_ = 0; i_ < 4; ++i_)                                                      \
      af[i_] = *(const i32x4*)(Ab + (wm * 128 + (4 + i_) * 16 + rl) * 64 + sws16);      \
    __builtin_amdgcn_s_setprio(1);                                                      \
    _Pragma("unroll")                                                                   \
    for (int i_ = 0; i_ < 4; ++i_)                                                      \
      _Pragma("unroll")                                                                 \
      for (int j_ = 0; j_ < 4; ++j_)                                                    \
        acc[4 + i_][j_] = __builtin_amdgcn_mfma_i32_16x16x64_i8(af[i_], bfr[j_],        \
                                                                acc[4 + i_][j_], 0, 0, 0); \
    __builtin_amdgcn_s_setprio(0);                                                      \
  }

#define VMC(n)  asm volatile("s_waitcnt vmcnt(" #n ")" ::: "memory")
#define BAR()   __builtin_amdgcn_s_barrier()

  // prologue: stage tiles 0,1,2 (12 loads/thread in flight)
  STAGE(0)
  STAGE(1)
  STAGE(2)

  for (int t = 0; t < NTI - 3; ++t) {         // t = 0..9
    VMC(8);
    BAR();
    asm volatile("" ::: "memory");
    STAGE(t + 3)
    COMPUTE(t & 3)
  }
  // t=10 (buf 2): tiles 11,12 in flight (8)
  VMC(8); BAR(); asm volatile("" ::: "memory");
  COMPUTE(2)
  // t=11 (buf 3): tile 12 in flight (4)
  VMC(4); BAR(); asm volatile("" ::: "memory");
  COMPUTE(3)
  // t=12 (buf 0): drain
  VMC(0); BAR(); asm volatile("" ::: "memory");
  COMPUTE(0)

#undef STAGE
#undef COMPUTE

  // ===== fused epilogue: dequant + relu -> LDS tile -> segmented sum -> agg atomics =====
  BAR();  // all waves done with ring LDS

  u16* tile = (u16*)lds;                        // [256][268] u16
  int* nseg = (int*)(lds + 137216);             // 256 ints
  float* sAl = (float*)(lds + 138240);          // 256 floats
  for (int i = tid; i < 256; i += 512) {
    nseg[i] = nsort[bm + i];
    sAl[i] = sA[bm + i];
  }
  __syncthreads();

  const int rq = (lane >> 4) * 4;
  const int cl = lane & 15;
#pragma unroll
  for (int j = 0; j < 4; ++j) {
    const int col16 = wn * 64 + j * 16 + cl;
    const float swn = sW[bn + col16];
    const float bj = bias[bn + col16];
#pragma unroll
    for (int mf = 0; mf < 8; ++mf) {
      const int r0 = wm * 128 + mf * 16 + rq;
#pragma unroll
      for (int q = 0; q < 4; ++q) {
        const int r = r0 + q;
        const float v = fmaf((float)acc[mf][j][q], sAl[r] * swn, bj);
        tile[r * 268 + col16] = f2bf(v > 0.f ? v : 0.f);
      }
    }
  }
  __syncthreads();

  // segmented column sums: threads 0..255 rows 0..127 of col tid; 256..511 rows 128..255
  const int col = tid & 255;
  const int rbase = (tid >> 8) * 128;
  float s = 0.f;
  int cur = -1;
  for (int r = 0; r < 128; ++r) {
    const int nd = nseg[rbase + r];
    const float v = bf2f(tile[(rbase + r) * 268 + col]);
    if (nd != cur) {
      if (cur >= 0) atomicAdd(&agg[(size_t)cur * D_N + bn + col], s);
      s = 0.f;
      cur = nd;
    }
    if (nd >= 0) s += v;
  }
  if (cur >= 0) atomicAdd(&agg[(size_t)cur * D_N + bn + col], s);

#undef VMC
#undef BAR
}

// ---------------- GIN combine: h = (1+eps)*x + agg -> bf16 ----------------
__global__ void k_build_h(const float* __restrict__ x, const float* __restrict__ agg,
                          const float* __restrict__ epsp, u16* __restrict__ hbf) {
  int i = blockIdx.x * 256 + threadIdx.x;
  if (i >= U_N * D_N) return;
  float h = (1.f + epsp[0]) * x[i] + agg[i];
  hbf[i] = f2bf(h);
}

// ---------------- generic bf16 GEMM (m97 structure), C f32 [M][N], K%64==0 ----------------
__global__ __launch_bounds__(256)
void gemm_bf16_g(const u16* __restrict__ A, const u16* __restrict__ B,
                 float* __restrict__ C, int ntn, int K) {
  __shared__ u16 As[128 * 64];
  __shared__ u16 Bs[128 * 64];
  const int bm = (blockIdx.x / ntn) * 128;
  const int bn = (blockIdx.x % ntn) * 128;
  const int t = threadIdx.x;
  const int wave = t >> 6, lane = t & 63;
  const int wr = (wave & 1) * 64, wc = (wave >> 1) * 64;
  const int srow = lane >> 3, scol = (lane & 7) * 8;
  const int rl = lane & 15, kl = (lane >> 4) * 8;
  const int N = ntn * 128;
  f32x4 acc[4][4] = {};
  for (int k0 = 0; k0 < K; k0 += 64) {
#pragma unroll
    for (int q = 0; q < 4; q++) {
      const int c = wave * 4 + q;
      const int row = c * 8 + srow;
      gload16(A + (size_t)(bm + row) * K + k0 + scol, As + c * 512);
      gload16(B + (size_t)(bn + row) * K + k0 + scol, Bs + c * 512);
    }
    __syncthreads();
#pragma unroll
    for (int ks = 0; ks < 2; ks++) {
      s16x8 af[4], bfr[4];
#pragma unroll
      for (int i = 0; i < 4; i++) af[i] = *(const s16x8*)&As[(wr + i * 16 + rl) * 64 + ks * 32 + kl];
#pragma unroll
      for (int j = 0; j < 4; j++) bfr[j] = *(const s16x8*)&Bs[(wc + j * 16 + rl) * 64 + ks * 32 + kl];
#pragma unroll
      for (int i = 0; i < 4; i++)
#pragma unroll
        for (int j = 0; j < 4; j++)
          acc[i][j] = __builtin_amdgcn_mfma_f32_16x16x32_bf16(af[i], bfr[j], acc[i][j], 0, 0, 0);
    }
    __syncthreads();
  }
  const int cl = lane & 15, rq = (lane >> 4) * 4;
#pragma unroll
  for (int i = 0; i < 4; i++)
#pragma unroll
    for (int j = 0; j < 4; j++) {
      const int n = bn + wc + j * 16 + cl;
      const int r = bm + wr + i * 16 + rq;
#pragma unroll
      for (int q = 0; q < 4; q++)
        C[(size_t)(r + q) * N + n] = acc[i][j][q];
    }
}

// ---------------- BN ----------------
__global__ void k_bnstats(const float* __restrict__ h1, float* __restrict__ ssum,
                          float* __restrict__ ssq) {
  const int cchunk = blockIdx.x % 3;
  const int rchunk = blockIdx.x / 3;
  const int c = cchunk * 256 + threadIdx.x;
  const int r0 = rchunk * 256;
  float s = 0.f, s2 = 0.f;
  for (int r = r0; r < r0 + 256; r++) {
    float v = h1[(size_t)r * D_N + c];
    s += v; s2 += v * v;
  }
  atomicAdd(&ssum[c], s);
  atomicAdd(&ssq[c], s2);
}

__global__ void k_bnfinal(const float* __restrict__ ssum, const float* __restrict__ ssq,
                          const float* __restrict__ gamma, const float* __restrict__ beta,
                          float* __restrict__ scale, float* __restrict__ shift) {
  int c = blockIdx.x * 256 + threadIdx.x;
  if (c >= D_N) return;
  double mean = (double)ssum[c] / (double)U_N;
  double var = (double)ssq[c] / (double)U_N - mean * mean;
  float sc = (float)((double)gamma[c] / sqrt(var + (double)BN_EPS));
  scale[c] = sc;
  shift[c] = beta[c] - (float)mean * sc;
}

__global__ void k_bnapply(const float* __restrict__ h1, const float* __restrict__ scale,
                          const float* __restrict__ shift, u16* __restrict__ h2) {
  int i = blockIdx.x * 256 + threadIdx.x;
  if (i >= U_N * D_N) return;
  int c = i % D_N;
  float v = h1[i] * scale[c] + shift[c];
  h2[i] = f2bf(v > 0.f ? v : 0.f);
}

extern "C" void kernel_launch(void* const* d_in, const int* in_sizes, int n_in,
                              void* d_out, int out_size, void* d_ws, size_t ws_size,
                              hipStream_t stream) {
  const float* x     = (const float*)d_in[0];
  const int*   uniq  = (const int*)d_in[1];
  const int*   srcg  = (const int*)d_in[2];
  const float* tgt   = (const float*)d_in[3];
  const float* edg   = (const float*)d_in[4];
  const float* Wedge = (const float*)d_in[5];
  const float* bedge = (const float*)d_in[6];
  const float* W1    = (const float*)d_in[7];
  const float* W2    = (const float*)d_in[8];
  const float* gamma = (const float*)d_in[9];
  const float* beta  = (const float*)d_in[10];
  const float* epsp  = (const float*)d_in[11];
  float* out = (float*)d_out;
  char* ws = (char*)d_ws;

  char*  Aq    = (char*) (ws + 0);             // 166,559,744
  float* agg   = (float*)(ws + 166559744ull);  // 25,165,824
  float* h1    = (float*)(ws + 191725568ull);  // 25,165,824
  u16*   hbf   = (u16*)  (ws + 216891392ull);  // 12,582,912
  u16*   h2b   = (u16*)  (ws + 229474304ull);  // 12,582,912
  char*  Wq    = (char*) (ws + 242057216ull);  // 638,976
  u16*   w1b   = (u16*)  (ws + 242696192ull);  // 1,179,648
  u16*   w2b   = (u16*)  (ws + 243875840ull);  // 1,179,648
  float* sA    = (float*)(ws + 245055488ull);  // 800,768
  float* sW    = (float*)(ws + 245856256ull);  // 4,096
  int*   lidx  = (int*)  (ws + 245860352ull);  // 800,000
  int*   eord  = (int*)  (ws + 246660352ull);  // 800,000
  int*   nsort = (int*)  (ws + 247460352ull);  // 800,768 (M_PAD)
  int*   counts= (int*)  (ws + 248261120ull);  // 32,768
  int*   cursor= (int*)  (ws + 248293888ull);  // 32,768
  int*   starts= (int*)  (ws + 248326656ull);  // 33,024
  float* ssum  = (float*)(ws + 248359680ull);  // 3,072
  float* ssq   = (float*)(ws + 248362752ull);
  float* scale = (float*)(ws + 248365824ull);
  float* shift = (float*)(ws + 248368896ull);

  hipMemsetAsync(counts, 0, 65536, stream);                 // counts + cursor
  hipMemsetAsync(ssum, 0, 2 * D_N * 4, stream);             // ssum + ssq
  hipMemsetAsync(agg, 0, (size_t)U_N * D_N * 4, stream);    // agg zeros
  hipMemsetAsync(nsort + E_N, 0xFF, (M_PAD - E_N) * 4, stream);  // pad rows -> -1

  k_convw_q8<<<D_N / 4, 256, 0, stream>>>(Wedge, Wq, sW);
  k_conv_w<<<(D_N * D_N + 255) / 256, 256, 0, stream>>>(W1, w1b, D_N * D_N);
  k_conv_w<<<(D_N * D_N + 255) / 256, 256, 0, stream>>>(W2, w2b, D_N * D_N);

  k_localidx<<<(E_N + 255) / 256, 256, 0, stream>>>(uniq, srcg, lidx);
  k_hist<<<(E_N + 255) / 256, 256, 0, stream>>>(lidx, counts);
  k_scan<<<1, 1024, 0, stream>>>(counts, starts);
  k_scatter<<<(E_N + 255) / 256, 256, 0, stream>>>(lidx, starts, cursor, eord, nsort);

  // pack+quantize in sorted order
  k_pack_q8<<<E_N / 4, 256, 0, stream>>>(tgt, edg, eord, Aq, sA);

  // fused int8 GEMM + dequant + segment-sum
  gemm_edge7<<<782 * 3, 512, 0, stream>>>(Aq, Wq, sA, sW, bedge, nsort, agg);

  k_build_h<<<(U_N * D_N + 255) / 256, 256, 0, stream>>>(x, agg, epsp, hbf);

  gemm_bf16_g<<<(U_N / 128) * 6, 256, 0, stream>>>(hbf, w1b, h1, 6, D_N);

  k_bnstats<<<96, 256, 0, stream>>>(h1, ssum, ssq);
  k_bnfinal<<<3, 256, 0, stream>>>(ssum, ssq, gamma, beta, scale, shift);
  k_bnapply<<<(U_N * D_N + 255) / 256, 256, 0, stream>>>(h1, scale, shift, h2b);

  gemm_bf16_g<<<(U_N / 128) * 6, 256, 0, stream>>>(h2b, w2b, out, 6, D_N);
}

// Round 8
// 569.084 us; speedup vs baseline: 1.4884x; 1.0255x over previous
//
#include <hip/hip_runtime.h>
#include <stdint.h>
#include <math.h>

typedef unsigned short u16;
typedef __attribute__((ext_vector_type(4))) float f32x4;
typedef __attribute__((ext_vector_type(8))) short s16x8;
typedef __attribute__((ext_vector_type(4))) int i32x4;

#define U_N 8192
#define E_N 200000
#define M_PAD 200192   // 782 * 256
#define D_N 768
#define DE_N 50
#define KP8 896        // 7 * 128 (zero-padded from 818)
#define NTI8 7
#define BN_EPS 1e-5f

__device__ __forceinline__ u16 f2bf(float f) {
  union { float f; unsigned u; } v; v.f = f;
  return (u16)((v.u + 0x7fffu + ((v.u >> 16) & 1u)) >> 16);
}
__device__ __forceinline__ float bf2f(u16 v) {
  union { unsigned u; float f; } x; x.u = ((unsigned)v) << 16; return x.f;
}
__device__ __forceinline__ void gload16(const void* g, void* l) {
  __builtin_amdgcn_global_load_lds((const __attribute__((address_space(1))) void*)g,
                                   (__attribute__((address_space(3))) void*)l, 16, 0, 0);
}

// ---------------- searchsorted (left) ----------------
__global__ void k_localidx(const int* __restrict__ uniq, const int* __restrict__ src,
                           int* __restrict__ lidx) {
  int e = blockIdx.x * 256 + threadIdx.x;
  if (e >= E_N) return;
  int v = src[e];
  int lo = 0, hi = U_N;
  while (lo < hi) { int mid = (lo + hi) >> 1; if (uniq[mid] < v) lo = mid + 1; else hi = mid; }
  lidx[e] = lo;
}

// ---------------- counting sort: hist / scan / scatter ----------------
__global__ void k_hist(const int* __restrict__ lidx, int* __restrict__ counts) {
  int e = blockIdx.x * 256 + threadIdx.x;
  if (e < E_N) atomicAdd(&counts[lidx[e]], 1);
}

__global__ void k_scan(const int* __restrict__ counts, int* __restrict__ starts) {
  __shared__ int part[1024];
  const int t = threadIdx.x;
  const int base = t * 8;
  int loc[8]; int s = 0;
#pragma unroll
  for (int i = 0; i < 8; i++) { loc[i] = s; s += counts[base + i]; }
  part[t] = s; __syncthreads();
  for (int off = 1; off < 1024; off <<= 1) {
    int v = (t >= off) ? part[t - off] : 0;
    __syncthreads();
    part[t] += v;
    __syncthreads();
  }
  const int pre = (t == 0) ? 0 : part[t - 1];
#pragma unroll
  for (int i = 0; i < 8; i++) starts[base + i] = pre + loc[i];
  if (t == 1023) starts[8192] = pre + s;
}

__global__ void k_scatter(const int* __restrict__ lidx, const int* __restrict__ starts,
                          int* __restrict__ cursor, int* __restrict__ eord,
                          int* __restrict__ nsort) {
  int e = blockIdx.x * 256 + threadIdx.x;
  if (e >= E_N) return;
  int u = lidx[e];
  int pos = atomicAdd(&cursor[u], 1);
  eord[starts[u] + pos] = e;
  nsort[starts[u] + pos] = u;
}

// ------- pack+quantize A (sorted order): Aq[pos][k] int8 (K padded to 896), per-row amax -------
__global__ __launch_bounds__(256)
void k_pack_q8(const float* __restrict__ tgt, const float* __restrict__ edg,
               const int* __restrict__ eord, char* __restrict__ Aq,
               float* __restrict__ sA) {
  const int row = blockIdx.x * 4 + (threadIdx.x >> 6);
  const int lane = threadIdx.x & 63;
  if (row >= E_N) return;
  const int e = eord[row];
  const int k0 = lane * 16;
  float v[16];
#pragma unroll
  for (int z = 0; z < 16; z++) v[z] = 0.f;
  if (k0 < D_N) {
    const f32x4* p = (const f32x4*)(tgt + (size_t)e * D_N + k0);
#pragma unroll
    for (int zz = 0; zz < 4; zz++) {
      const f32x4 f = p[zz];
#pragma unroll
      for (int b = 0; b < 4; b++) v[zz * 4 + b] = f[b];
    }
  } else if (k0 < KP8) {
#pragma unroll
    for (int z = 0; z < 16; z++) {
      const int kk = k0 + z - D_N;
      v[z] = (kk < DE_N) ? edg[(size_t)e * DE_N + kk] : 0.f;
    }
  }
  float am = 0.f;
#pragma unroll
  for (int z = 0; z < 16; z++) am = fmaxf(am, fabsf(v[z]));
#pragma unroll
  for (int off = 32; off > 0; off >>= 1) am = fmaxf(am, __shfl_xor(am, off));
  am = fmaxf(am, 1e-8f);
  const float inv = 127.f / am;
  if (lane == 0) sA[row] = am / 127.f;
  if (k0 < KP8) {
    int wq[4];
#pragma unroll
    for (int zz = 0; zz < 4; zz++) {
      int b0 = (int)rintf(fminf(fmaxf(v[zz*4+0] * inv, -127.f), 127.f));
      int b1 = (int)rintf(fminf(fmaxf(v[zz*4+1] * inv, -127.f), 127.f));
      int b2 = (int)rintf(fminf(fmaxf(v[zz*4+2] * inv, -127.f), 127.f));
      int b3 = (int)rintf(fminf(fmaxf(v[zz*4+3] * inv, -127.f), 127.f));
      wq[zz] = (b0 & 255) | ((b1 & 255) << 8) | ((b2 & 255) << 16) | (b3 << 24);
    }
    i32x4 out = {wq[0], wq[1], wq[2], wq[3]};
    *(i32x4*)(Aq + (size_t)row * KP8 + k0) = out;
  }
}

// ------- quantize W_edge rows (818 -> 896 pad), per-row amax -------
__global__ __launch_bounds__(256)
void k_convw_q8(const float* __restrict__ W, char* __restrict__ Wq,
                float* __restrict__ sW) {
  const int row = blockIdx.x * 4 + (threadIdx.x >> 6);
  const int lane = threadIdx.x & 63;
  if (row >= D_N) return;
  const int k0 = lane * 16;
  float v[16];
#pragma unroll
  for (int z = 0; z < 16; z++) v[z] = 0.f;
  if (k0 < KP8) {
#pragma unroll
    for (int z = 0; z < 16; z++) {
      const int kk = k0 + z;
      v[z] = (kk < D_N + DE_N) ? W[(size_t)row * (D_N + DE_N) + kk] : 0.f;
    }
  }
  float am = 0.f;
#pragma unroll
  for (int z = 0; z < 16; z++) am = fmaxf(am, fabsf(v[z]));
#pragma unroll
  for (int off = 32; off > 0; off >>= 1) am = fmaxf(am, __shfl_xor(am, off));
  am = fmaxf(am, 1e-8f);
  const float inv = 127.f / am;
  if (lane == 0) sW[row] = am / 127.f;
  if (k0 < KP8) {
    int wq[4];
#pragma unroll
    for (int zz = 0; zz < 4; zz++) {
      int b0 = (int)rintf(fminf(fmaxf(v[zz*4+0] * inv, -127.f), 127.f));
      int b1 = (int)rintf(fminf(fmaxf(v[zz*4+1] * inv, -127.f), 127.f));
      int b2 = (int)rintf(fminf(fmaxf(v[zz*4+2] * inv, -127.f), 127.f));
      int b3 = (int)rintf(fminf(fmaxf(v[zz*4+3] * inv, -127.f), 127.f));
      wq[zz] = (b0 & 255) | ((b1 & 255) << 8) | ((b2 & 255) << 16) | (b3 << 24);
    }
    i32x4 out = {wq[0], wq[1], wq[2], wq[3]};
    *(i32x4*)(Wq + (size_t)row * KP8 + k0) = out;
  }
}

// ---------------- weight conversion (bf16, for W1/W2) ----------------
__global__ void k_conv_w(const float* __restrict__ W, u16* __restrict__ Wb, int count) {
  int i = blockIdx.x * 256 + threadIdx.x;
  if (i < count) Wb[i] = f2bf(W[i]);
}

// ====== edge GEMM v8: int8, 256x256, BK=128 (7 tiles), ring-2, counted vmcnt ======
// LDS row stride 128 B = 8 x 16B slots; slot p of row r holds global slot p^(r&7)
// (both-sides involution). Per tile: 24 ds_read_b128 + 64 MFMA per wave, 2 barriers.
__global__ __launch_bounds__(512)
void gemm_edge8(const char* __restrict__ Aq, const char* __restrict__ Wq,
                const float* __restrict__ sA, const float* __restrict__ sW,
                const float* __restrict__ bias, const int* __restrict__ nsort,
                float* __restrict__ agg) {
  // ring: A 2x32KB at 0, B 2x32KB at 65536. Epilogue reuses [0,137216) as u16 [256][268].
  __shared__ char lds[139264];

  // bijective XCD swizzle, nwg = 2346 = 8*293 + 2
  const int orig = blockIdx.x;
  const int xcd = orig & 7, i8_ = orig >> 3;
  const int wgid = (xcd < 2 ? xcd * 294 : 588 + (xcd - 2) * 293) + i8_;
  const int bm = (wgid / 3) * 256;
  const int bn = (wgid % 3) * 256;

  const int tid = threadIdx.x;
  const int w = tid >> 6, lane = tid & 63;
  const int wm = w >> 2, wn = w & 3;          // wave tile: rows wm*128, cols wn*64
  const int rl = lane & 15, K16 = lane >> 4;
  // staging decode: chunk cc = c*8+w (1 KB each = 8 rows x 8 slots); lane -> row lane>>3, slot lane&7
  const int srr = lane >> 3;
  const int ssrc = (lane & 7) ^ srr;          // source slot for linear LDS dest

  i32x4 acc[8][4] = {};

#define STAGE8(T)                                                                       \
  {                                                                                     \
    const int b_ = (T) & 1;                                                             \
    const int k0_ = (T) * 128;                                                          \
    _Pragma("unroll")                                                                   \
    for (int c_ = 0; c_ < 4; ++c_) {                                                    \
      const int cc_ = c_ * 8 + w;                                                       \
      const int r_ = cc_ * 8 + srr;                                                     \
      gload16(Aq + (size_t)(bm + r_) * KP8 + k0_ + ssrc * 16, lds + b_ * 32768 + cc_ * 1024); \
    }                                                                                   \
    _Pragma("unroll")                                                                   \
    for (int c_ = 0; c_ < 4; ++c_) {                                                    \
      const int cc_ = c_ * 8 + w;                                                       \
      const int r_ = cc_ * 8 + srr;                                                     \
      gload16(Wq + (size_t)(bn + r_) * KP8 + k0_ + ssrc * 16, lds + 65536 + b_ * 32768 + cc_ * 1024); \
    }                                                                                   \
  }

#define COMPUTE_H(BB, h_)                                                               \
  {                                                                                     \
    const char* Ab = lds + (BB) * 32768;                                                \
    const char* Bb = lds + 65536 + (BB) * 32768;                                        \
    const int sb_ = (h_) * 4 + K16;                                                     \
    const int sw_ = (sb_ ^ (rl & 7)) * 16;                                              \
    i32x4 bfr[4], af[4];                                                                \
    _Pragma("unroll")                                                                   \
    for (int j_ = 0; j_ < 4; ++j_)                                                      \
      bfr[j_] = *(const i32x4*)(Bb + (wn * 64 + j_ * 16 + rl) * 128 + sw_);             \
    _Pragma("unroll")                                                                   \
    for (int i_ = 0; i_ < 4; ++i_)                                                      \
      af[i_] = *(const i32x4*)(Ab + (wm * 128 + i_ * 16 + rl) * 128 + sw_);             \
    __builtin_amdgcn_s_setprio(1);                                                      \
    _Pragma("unroll")                                                                   \
    for (int i_ = 0; i_ < 4; ++i_)                                                      \
      _Pragma("unroll")                                                                 \
      for (int j_ = 0; j_ < 4; ++j_)                                                    \
        acc[i_][j_] = __builtin_amdgcn_mfma_i32_16x16x64_i8(af[i_], bfr[j_],            \
                                                            acc[i_][j_], 0, 0, 0);     \
    __builtin_amdgcn_s_setprio(0);                                                      \
    _Pragma("unroll")                                                                   \
    for (int i_ = 0; i_ < 4; ++i_)                                                      \
      af[i_] = *(const i32x4*)(Ab + (wm * 128 + (4 + i_) * 16 + rl) * 128 + sw_);       \
    __builtin_amdgcn_s_setprio(1);                                                      \
    _Pragma("unroll")                                                                   \
    for (int i_ = 0; i_ < 4; ++i_)                                                      \
      _Pragma("unroll")                                                                 \
      for (int j_ = 0; j_ < 4; ++j_)                                                    \
        acc[4 + i_][j_] = __builtin_amdgcn_mfma_i32_16x16x64_i8(af[i_], bfr[j_],        \
                                                                acc[4 + i_][j_], 0, 0, 0); \
    __builtin_amdgcn_s_setprio(0);                                                      \
  }

#define VMC(n)  asm volatile("s_waitcnt vmcnt(" #n ")" ::: "memory")
#define BAR()   __builtin_amdgcn_s_barrier()

  STAGE8(0)
  for (int t = 0; t < NTI8 - 1; ++t) {        // t = 0..5
    BAR();                                    // fence compute(t-1) before overwriting its buffer
    STAGE8(t + 1)
    VMC(8);                                   // tile t landed (t+1's 8 loads outstanding)
    BAR();
    asm volatile("" ::: "memory");
    COMPUTE_H(t & 1, 0)
    COMPUTE_H(t & 1, 1)
  }
  BAR();
  VMC(0);
  BAR();
  asm volatile("" ::: "memory");
  COMPUTE_H(0, 0)                             // t=6 -> buf 0
  COMPUTE_H(0, 1)

#undef STAGE8
#undef COMPUTE_H

  // ===== fused epilogue: dequant + relu -> LDS tile -> segmented sum -> agg atomics =====
  BAR();

  u16* tile = (u16*)lds;                        // [256][268] u16
  int* nseg = (int*)(lds + 137216);             // 256 ints
  float* sAl = (float*)(lds + 138240);          // 256 floats
  for (int i = tid; i < 256; i += 512) {
    nseg[i] = nsort[bm + i];
    sAl[i] = sA[bm + i];
  }
  __syncthreads();

  const int rq = (lane >> 4) * 4;
  const int cl = lane & 15;
#pragma unroll
  for (int j = 0; j < 4; ++j) {
    const int col16 = wn * 64 + j * 16 + cl;
    const float swn = sW[bn + col16];
    const float bj = bias[bn + col16];
#pragma unroll
    for (int mf = 0; mf < 8; ++mf) {
      const int r0 = wm * 128 + mf * 16 + rq;
#pragma unroll
      for (int q = 0; q < 4; ++q) {
        const int r = r0 + q;
        const float v = fmaf((float)acc[mf][j][q], sAl[r] * swn, bj);
        tile[r * 268 + col16] = f2bf(v > 0.f ? v : 0.f);
      }
    }
  }
  __syncthreads();

  const int col = tid & 255;
  const int rbase = (tid >> 8) * 128;
  float s = 0.f;
  int cur = -1;
  for (int r = 0; r < 128; ++r) {
    const int nd = nseg[rbase + r];
    const float v = bf2f(tile[(rbase + r) * 268 + col]);
    if (nd != cur) {
      if (cur >= 0) atomicAdd(&agg[(size_t)cur * D_N + bn + col], s);
      s = 0.f;
      cur = nd;
    }
    if (nd >= 0) s += v;
  }
  if (cur >= 0) atomicAdd(&agg[(size_t)cur * D_N + bn + col], s);

#undef VMC
#undef BAR
}

// ---------------- GIN combine: h = (1+eps)*x + agg -> bf16 ----------------
__global__ void k_build_h(const float* __restrict__ x, const float* __restrict__ agg,
                          const float* __restrict__ epsp, u16* __restrict__ hbf) {
  int i = blockIdx.x * 256 + threadIdx.x;
  if (i >= U_N * D_N) return;
  float h = (1.f + epsp[0]) * x[i] + agg[i];
  hbf[i] = f2bf(h);
}

// ------- h1 GEMM: h1b = bf16(hbf @ W1^T), fused BN partial stats (ssum/ssq atomics) -------
__global__ __launch_bounds__(256)
void gemm_h1(const u16* __restrict__ A, const u16* __restrict__ B,
             u16* __restrict__ h1b, float* __restrict__ ssum, float* __restrict__ ssq) {
  __shared__ u16 As[128 * 64];
  __shared__ u16 Bs[128 * 64];
  const int bm = (blockIdx.x / 6) * 128;
  const int bn = (blockIdx.x % 6) * 128;
  const int t = threadIdx.x;
  const int wave = t >> 6, lane = t & 63;
  const int wr = (wave & 1) * 64, wc = (wave >> 1) * 64;
  const int srow = lane >> 3, scol = (lane & 7) * 8;
  const int rl = lane & 15, kl = (lane >> 4) * 8;
  f32x4 acc[4][4] = {};
  for (int k0 = 0; k0 < D_N; k0 += 64) {
#pragma unroll
    for (int q = 0; q < 4; q++) {
      const int c = wave * 4 + q;
      const int row = c * 8 + srow;
      gload16(A + (size_t)(bm + row) * D_N + k0 + scol, As + c * 512);
      gload16(B + (size_t)(bn + row) * D_N + k0 + scol, Bs + c * 512);
    }
    __syncthreads();
#pragma unroll
    for (int ks = 0; ks < 2; ks++) {
      s16x8 af[4], bfr[4];
#pragma unroll
      for (int i = 0; i < 4; i++) af[i] = *(const s16x8*)&As[(wr + i * 16 + rl) * 64 + ks * 32 + kl];
#pragma unroll
      for (int j = 0; j < 4; j++) bfr[j] = *(const s16x8*)&Bs[(wc + j * 16 + rl) * 64 + ks * 32 + kl];
#pragma unroll
      for (int i = 0; i < 4; i++)
#pragma unroll
        for (int j = 0; j < 4; j++)
          acc[i][j] = __builtin_amdgcn_mfma_f32_16x16x32_bf16(af[i], bfr[j], acc[i][j], 0, 0, 0);
    }
    __syncthreads();
  }
  const int cl = lane & 15, rq = (lane >> 4) * 4;
#pragma unroll
  for (int j = 0; j < 4; j++) {
    const int n = bn + wc + j * 16 + cl;
    float cs = 0.f, cq = 0.f;
#pragma unroll
    for (int i = 0; i < 4; i++) {
      const int r = bm + wr + i * 16 + rq;
#pragma unroll
      for (int q = 0; q < 4; q++) {
        const float v = acc[i][j][q];
        cs += v; cq += v * v;
        h1b[(size_t)(r + q) * D_N + n] = f2bf(v);
      }
    }
    cs += __shfl_xor(cs, 16); cq += __shfl_xor(cq, 16);
    cs += __shfl_xor(cs, 32); cq += __shfl_xor(cq, 32);
    if (lane < 16) { atomicAdd(&ssum[n], cs); atomicAdd(&ssq[n], cq); }
  }
}

// ---------------- generic bf16 GEMM (m97 structure), C f32 [M][N], K%64==0 ----------------
__global__ __launch_bounds__(256)
void gemm_bf16_g(const u16* __restrict__ A, const u16* __restrict__ B,
                 float* __restrict__ C, int ntn, int K) {
  __shared__ u16 As[128 * 64];
  __shared__ u16 Bs[128 * 64];
  const int bm = (blockIdx.x / ntn) * 128;
  const int bn = (blockIdx.x % ntn) * 128;
  const int t = threadIdx.x;
  const int wave = t >> 6, lane = t & 63;
  const int wr = (wave & 1) * 64, wc = (wave >> 1) * 64;
  const int srow = lane >> 3, scol = (lane & 7) * 8;
  const int rl = lane & 15, kl = (lane >> 4) * 8;
  const int N = ntn * 128;
  f32x4 acc[4][4] = {};
  for (int k0 = 0; k0 < K; k0 += 64) {
#pragma unroll
    for (int q = 0; q < 4; q++) {
      const int c = wave * 4 + q;
      const int row = c * 8 + srow;
      gload16(A + (size_t)(bm + row) * K + k0 + scol, As + c * 512);
      gload16(B + (size_t)(bn + row) * K + k0 + scol, Bs + c * 512);
    }
    __syncthreads();
#pragma unroll
    for (int ks = 0; ks < 2; ks++) {
      s16x8 af[4], bfr[4];
#pragma unroll
      for (int i = 0; i < 4; i++) af[i] = *(const s16x8*)&As[(wr + i * 16 + rl) * 64 + ks * 32 + kl];
#pragma unroll
      for (int j = 0; j < 4; j++) bfr[j] = *(const s16x8*)&Bs[(wc + j * 16 + rl) * 64 + ks * 32 + kl];
#pragma unroll
      for (int i = 0; i < 4; i++)
#pragma unroll
        for (int j = 0; j < 4; j++)
          acc[i][j] = __builtin_amdgcn_mfma_f32_16x16x32_bf16(af[i], bfr[j], acc[i][j], 0, 0, 0);
    }
    __syncthreads();
  }
  const int cl = lane & 15, rq = (lane >> 4) * 4;
#pragma unroll
  for (int i = 0; i < 4; i++)
#pragma unroll
    for (int j = 0; j < 4; j++) {
      const int n = bn + wc + j * 16 + cl;
      const int r = bm + wr + i * 16 + rq;
#pragma unroll
      for (int q = 0; q < 4; q++)
        C[(size_t)(r + q) * N + n] = acc[i][j][q];
    }
}

// ---------------- BN ----------------
__global__ void k_bnfinal(const float* __restrict__ ssum, const float* __restrict__ ssq,
                          const float* __restrict__ gamma, const float* __restrict__ beta,
                          float* __restrict__ scale, float* __restrict__ shift) {
  int c = blockIdx.x * 256 + threadIdx.x;
  if (c >= D_N) return;
  double mean = (double)ssum[c] / (double)U_N;
  double var = (double)ssq[c] / (double)U_N - mean * mean;
  float sc = (float)((double)gamma[c] / sqrt(var + (double)BN_EPS));
  scale[c] = sc;
  shift[c] = beta[c] - (float)mean * sc;
}

__global__ void k_bnapply(const u16* __restrict__ h1b, const float* __restrict__ scale,
                          const float* __restrict__ shift, u16* __restrict__ h2) {
  int i = blockIdx.x * 256 + threadIdx.x;
  if (i >= U_N * D_N) return;
  int c = i % D_N;
  float v = bf2f(h1b[i]) * scale[c] + shift[c];
  h2[i] = f2bf(v > 0.f ? v : 0.f);
}

extern "C" void kernel_launch(void* const* d_in, const int* in_sizes, int n_in,
                              void* d_out, int out_size, void* d_ws, size_t ws_size,
                              hipStream_t stream) {
  const float* x     = (const float*)d_in[0];
  const int*   uniq  = (const int*)d_in[1];
  const int*   srcg  = (const int*)d_in[2];
  const float* tgt   = (const float*)d_in[3];
  const float* edg   = (const float*)d_in[4];
  const float* Wedge = (const float*)d_in[5];
  const float* bedge = (const float*)d_in[6];
  const float* W1    = (const float*)d_in[7];
  const float* W2    = (const float*)d_in[8];
  const float* gamma = (const float*)d_in[9];
  const float* beta  = (const float*)d_in[10];
  const float* epsp  = (const float*)d_in[11];
  float* out = (float*)d_out;
  char* ws = (char*)d_ws;

  char*  Aq    = (char*) (ws + 0);             // 179,372,032 (M_PAD x 896)
  float* agg   = (float*)(ws + 179372032ull);  // 25,165,824
  u16*   h1b   = (u16*)  (ws + 204537856ull);  // 12,582,912
  u16*   hbf   = (u16*)  (ws + 217120768ull);  // 12,582,912
  u16*   h2b   = (u16*)  (ws + 229703680ull);  // 12,582,912
  char*  Wq    = (char*) (ws + 242286592ull);  // 688,128
  u16*   w1b   = (u16*)  (ws + 242974720ull);  // 1,179,648
  u16*   w2b   = (u16*)  (ws + 244154368ull);  // 1,179,648
  float* sA    = (float*)(ws + 245334016ull);  // 800,768
  float* sW    = (float*)(ws + 246134784ull);  // 4,096
  int*   lidx  = (int*)  (ws + 246138880ull);  // 800,000
  int*   eord  = (int*)  (ws + 246938880ull);  // 800,000
  int*   nsort = (int*)  (ws + 247738880ull);  // 800,768 (M_PAD)
  int*   counts= (int*)  (ws + 248539648ull);  // 32,768
  int*   cursor= (int*)  (ws + 248572416ull);  // 32,768
  int*   starts= (int*)  (ws + 248605184ull);  // 33,024
  float* ssum  = (float*)(ws + 248638208ull);  // 3,072
  float* ssq   = (float*)(ws + 248641280ull);
  float* scale = (float*)(ws + 248644352ull);
  float* shift = (float*)(ws + 248647424ull);

  hipMemsetAsync(counts, 0, 65536, stream);                 // counts + cursor
  hipMemsetAsync(ssum, 0, 2 * D_N * 4, stream);             // ssum + ssq
  hipMemsetAsync(agg, 0, (size_t)U_N * D_N * 4, stream);    // agg zeros
  hipMemsetAsync(nsort + E_N, 0xFF, (M_PAD - E_N) * 4, stream);  // pad rows -> -1

  k_convw_q8<<<D_N / 4, 256, 0, stream>>>(Wedge, Wq, sW);
  k_conv_w<<<(D_N * D_N + 255) / 256, 256, 0, stream>>>(W1, w1b, D_N * D_N);
  k_conv_w<<<(D_N * D_N + 255) / 256, 256, 0, stream>>>(W2, w2b, D_N * D_N);

  k_localidx<<<(E_N + 255) / 256, 256, 0, stream>>>(uniq, srcg, lidx);
  k_hist<<<(E_N + 255) / 256, 256, 0, stream>>>(lidx, counts);
  k_scan<<<1, 1024, 0, stream>>>(counts, starts);
  k_scatter<<<(E_N + 255) / 256, 256, 0, stream>>>(lidx, starts, cursor, eord, nsort);

  k_pack_q8<<<E_N / 4, 256, 0, stream>>>(tgt, edg, eord, Aq, sA);

  gemm_edge8<<<782 * 3, 512, 0, stream>>>(Aq, Wq, sA, sW, bedge, nsort, agg);

  k_build_h<<<(U_N * D_N + 255) / 256, 256, 0, stream>>>(x, agg, epsp, hbf);

  gemm_h1<<<(U_N / 128) * 6, 256, 0, stream>>>(hbf, w1b, h1b, ssum, ssq);

  k_bnfinal<<<3, 256, 0, stream>>>(ssum, ssq, gamma, beta, scale, shift);
  k_bnapply<<<(U_N * D_N + 255) / 256, 256, 0, stream>>>(h1b, scale, shift, h2b);

  gemm_bf16_g<<<(U_N / 128) * 6, 256, 0, stream>>>(h2b, w2b, out, 6, D_N);
}

// Round 9
// 500.857 us; speedup vs baseline: 1.6911x; 1.1362x over previous
//
#include <hip/hip_runtime.h>
#include <stdint.h>
#include <math.h>

typedef unsigned short u16;
typedef __attribute__((ext_vector_type(4))) float f32x4;
typedef __attribute__((ext_vector_type(8))) short s16x8;
typedef __attribute__((ext_vector_type(4))) int i32x4;

#define U_N 8192
#define E_N 200000
#define M_PAD 200064   // 1563 * 128
#define NMT 1563
#define D_N 768
#define DE_N 50
#define KP_E 832       // 13 * 64
#define NTI 13
#define BN_EPS 1e-5f

__device__ __forceinline__ u16 f2bf(float f) {
  union { float f; unsigned u; } v; v.f = f;
  return (u16)((v.u + 0x7fffu + ((v.u >> 16) & 1u)) >> 16);
}
__device__ __forceinline__ float bf2f(u16 v) {
  union { unsigned u; float f; } x; x.u = ((unsigned)v) << 16; return x.f;
}
__device__ __forceinline__ void gload16(const void* g, void* l) {
  __builtin_amdgcn_global_load_lds((const __attribute__((address_space(1))) void*)g,
                                   (__attribute__((address_space(3))) void*)l, 16, 0, 0);
}

// ---------------- searchsorted + histogram (merged) ----------------
__global__ void k_lh(const int* __restrict__ uniq, const int* __restrict__ src,
                     int* __restrict__ lidx, int* __restrict__ counts) {
  int e = blockIdx.x * 256 + threadIdx.x;
  if (e >= E_N) return;
  int v = src[e];
  int lo = 0, hi = U_N;
  while (lo < hi) { int mid = (lo + hi) >> 1; if (uniq[mid] < v) lo = mid + 1; else hi = mid; }
  lidx[e] = lo;
  atomicAdd(&counts[lo], 1);
}

__global__ void k_scan(const int* __restrict__ counts, int* __restrict__ starts) {
  __shared__ int part[1024];
  const int t = threadIdx.x;
  const int base = t * 8;
  int loc[8]; int s = 0;
#pragma unroll
  for (int i = 0; i < 8; i++) { loc[i] = s; s += counts[base + i]; }
  part[t] = s; __syncthreads();
  for (int off = 1; off < 1024; off <<= 1) {
    int v = (t >= off) ? part[t - off] : 0;
    __syncthreads();
    part[t] += v;
    __syncthreads();
  }
  const int pre = (t == 0) ? 0 : part[t - 1];
#pragma unroll
  for (int i = 0; i < 8; i++) starts[base + i] = pre + loc[i];
  if (t == 1023) starts[8192] = pre + s;
}

__global__ void k_scatter(const int* __restrict__ lidx, const int* __restrict__ starts,
                          int* __restrict__ cursor, int* __restrict__ eord,
                          int* __restrict__ nsort) {
  int e = blockIdx.x * 256 + threadIdx.x;
  if (e >= E_N) return;
  int u = lidx[e];
  int pos = atomicAdd(&cursor[u], 1);
  eord[starts[u] + pos] = e;
  nsort[starts[u] + pos] = u;
}

// ------- pack+quantize A (sorted order): Aq[pos][k] int8 (K=832), per-row amax -------
__global__ __launch_bounds__(256)
void k_pack_q8(const float* __restrict__ tgt, const float* __restrict__ edg,
               const int* __restrict__ eord, char* __restrict__ Aq,
               float* __restrict__ sA) {
  const int row = blockIdx.x * 4 + (threadIdx.x >> 6);
  const int lane = threadIdx.x & 63;
  if (row >= E_N) return;
  const int e = eord[row];
  const int k0 = lane * 16;
  float v[16];
#pragma unroll
  for (int z = 0; z < 16; z++) v[z] = 0.f;
  if (k0 < D_N) {
    const f32x4* p = (const f32x4*)(tgt + (size_t)e * D_N + k0);
#pragma unroll
    for (int zz = 0; zz < 4; zz++) {
      const f32x4 f = p[zz];
#pragma unroll
      for (int b = 0; b < 4; b++) v[zz * 4 + b] = f[b];
    }
  } else if (k0 < KP_E) {
#pragma unroll
    for (int z = 0; z < 16; z++) {
      const int kk = k0 + z - D_N;
      v[z] = (kk < DE_N) ? edg[(size_t)e * DE_N + kk] : 0.f;
    }
  }
  float am = 0.f;
#pragma unroll
  for (int z = 0; z < 16; z++) am = fmaxf(am, fabsf(v[z]));
#pragma unroll
  for (int off = 32; off > 0; off >>= 1) am = fmaxf(am, __shfl_xor(am, off));
  am = fmaxf(am, 1e-8f);
  const float inv = 127.f / am;
  if (lane == 0) sA[row] = am / 127.f;
  if (k0 < KP_E) {
    int wq[4];
#pragma unroll
    for (int zz = 0; zz < 4; zz++) {
      int b0 = (int)rintf(fminf(fmaxf(v[zz*4+0] * inv, -127.f), 127.f));
      int b1 = (int)rintf(fminf(fmaxf(v[zz*4+1] * inv, -127.f), 127.f));
      int b2 = (int)rintf(fminf(fmaxf(v[zz*4+2] * inv, -127.f), 127.f));
      int b3 = (int)rintf(fminf(fmaxf(v[zz*4+3] * inv, -127.f), 127.f));
      wq[zz] = (b0 & 255) | ((b1 & 255) << 8) | ((b2 & 255) << 16) | (b3 << 24);
    }
    i32x4 out = {wq[0], wq[1], wq[2], wq[3]};
    *(i32x4*)(Aq + (size_t)row * KP_E + k0) = out;
  }
}

// ------- quantize W_edge rows (818 -> 832 pad), per-row amax -------
__global__ __launch_bounds__(256)
void k_convw_q8(const float* __restrict__ W, char* __restrict__ Wq,
                float* __restrict__ sW) {
  const int row = blockIdx.x * 4 + (threadIdx.x >> 6);
  const int lane = threadIdx.x & 63;
  if (row >= D_N) return;
  const int k0 = lane * 16;
  float v[16];
#pragma unroll
  for (int z = 0; z < 16; z++) v[z] = 0.f;
  if (k0 < KP_E) {
#pragma unroll
    for (int z = 0; z < 16; z++) {
      const int kk = k0 + z;
      v[z] = (kk < D_N + DE_N) ? W[(size_t)row * (D_N + DE_N) + kk] : 0.f;
    }
  }
  float am = 0.f;
#pragma unroll
  for (int z = 0; z < 16; z++) am = fmaxf(am, fabsf(v[z]));
#pragma unroll
  for (int off = 32; off > 0; off >>= 1) am = fmaxf(am, __shfl_xor(am, off));
  am = fmaxf(am, 1e-8f);
  const float inv = 127.f / am;
  if (lane == 0) sW[row] = am / 127.f;
  if (k0 < KP_E) {
    int wq[4];
#pragma unroll
    for (int zz = 0; zz < 4; zz++) {
      int b0 = (int)rintf(fminf(fmaxf(v[zz*4+0] * inv, -127.f), 127.f));
      int b1 = (int)rintf(fminf(fmaxf(v[zz*4+1] * inv, -127.f), 127.f));
      int b2 = (int)rintf(fminf(fmaxf(v[zz*4+2] * inv, -127.f), 127.f));
      int b3 = (int)rintf(fminf(fmaxf(v[zz*4+3] * inv, -127.f), 127.f));
      wq[zz] = (b0 & 255) | ((b1 & 255) << 8) | ((b2 & 255) << 16) | (b3 << 24);
    }
    i32x4 out = {wq[0], wq[1], wq[2], wq[3]};
    *(i32x4*)(Wq + (size_t)row * KP_E + k0) = out;
  }
}

// ---------------- merged bf16 weight conversion (W1 + W2) ----------------
__global__ void k_conv_w2(const float* __restrict__ W1, const float* __restrict__ W2,
                          u16* __restrict__ w1b, u16* __restrict__ w2b) {
  int i = blockIdx.x * 256 + threadIdx.x;
  const int C = D_N * D_N;
  if (i < C) w1b[i] = f2bf(W1[i]);
  else if (i < 2 * C) w2b[i - C] = f2bf(W2[i - C]);
}

// ====== edge GEMM v9: int8, 128x128 tile, 4 waves, ring-2 BK=64, 4 blocks/CU ======
// Occupancy-first: acc 64 VGPR, LDS 34 KB -> 16 waves/CU (4 independent blocks).
// Swizzle (proven v7): LDS slot p of row r holds global slot p ^ ((r>>1)&3).
__global__ __launch_bounds__(256, 4)
void gemm_edge9(const char* __restrict__ Aq, const char* __restrict__ Wq,
                const float* __restrict__ sA, const float* __restrict__ sW,
                const float* __restrict__ bias, const int* __restrict__ nsort,
                float* __restrict__ agg) {
  // ring buf b at b*16384: A [128][64B] at +0, B [128][64B] at +8192.
  // epilogue: u16 tile[128][132] at 0 (33792 B); nseg at 33792; sAl at 34304.
  __shared__ char lds[34816];

  // bijective XCD swizzle, nwg = 9378 = 8*1172 + 2
  const int orig = blockIdx.x;
  const int xcd = orig & 7, i8_ = orig >> 3;
  const int wgid = (xcd < 2 ? xcd * 1173 : 2346 + (xcd - 2) * 1172) + i8_;
  const int bm = (wgid / 6) * 128;
  const int bn = (wgid % 6) * 128;

  const int tid = threadIdx.x;
  const int w = tid >> 6, lane = tid & 63;
  const int wm = w & 1, wn = w >> 1;          // wave tile: rows wm*64, cols wn*64
  const int rl = lane & 15, K16 = lane >> 4;
  const int sws = (K16 ^ ((rl >> 1) & 3)) * 16;
  // staging: entry e = tid (+256): row = e>>2, slot = e&3; src slot = slot ^ ((row>>1)&3)
  const int srow = tid >> 2;
  const int sg0 = (tid & 3) ^ ((srow >> 1) & 3);   // same for row srow+64 (64>>1 ≡ 0 mod 4)

  i32x4 acc[4][4] = {};

#define VMC(n)  asm volatile("s_waitcnt vmcnt(" #n ")" ::: "memory")
#define BAR()   __builtin_amdgcn_s_barrier()

#define STAGE9(T)                                                                       \
  {                                                                                     \
    const int b_ = (T) & 1;                                                             \
    const int k0_ = (T) * 64;                                                           \
    gload16(Aq + (size_t)(bm + srow) * KP_E + k0_ + sg0 * 16, lds + b_ * 16384 + tid * 16); \
    gload16(Aq + (size_t)(bm + srow + 64) * KP_E + k0_ + sg0 * 16, lds + b_ * 16384 + 4096 + tid * 16); \
    gload16(Wq + (size_t)(bn + srow) * KP_E + k0_ + sg0 * 16, lds + b_ * 16384 + 8192 + tid * 16); \
    gload16(Wq + (size_t)(bn + srow + 64) * KP_E + k0_ + sg0 * 16, lds + b_ * 16384 + 12288 + tid * 16); \
  }

#define COMPUTE9(BB)                                                                    \
  {                                                                                     \
    const char* Ab = lds + (BB) * 16384;                                                \
    const char* Bb = Ab + 8192;                                                         \
    i32x4 af[4], bfr[4];                                                                \
    _Pragma("unroll")                                                                   \
    for (int j_ = 0; j_ < 4; ++j_)                                                      \
      bfr[j_] = *(const i32x4*)(Bb + (wn * 64 + j_ * 16 + rl) * 64 + sws);              \
    _Pragma("unroll")                                                                   \
    for (int i_ = 0; i_ < 4; ++i_)                                                      \
      af[i_] = *(const i32x4*)(Ab + (wm * 64 + i_ * 16 + rl) * 64 + sws);               \
    __builtin_amdgcn_s_setprio(1);                                                      \
    _Pragma("unroll")                                                                   \
    for (int i_ = 0; i_ < 4; ++i_)                                                      \
      _Pragma("unroll")                                                                 \
      for (int j_ = 0; j_ < 4; ++j_)                                                    \
        acc[i_][j_] = __builtin_amdgcn_mfma_i32_16x16x64_i8(af[i_], bfr[j_],            \
                                                            acc[i_][j_], 0, 0, 0);     \
    __builtin_amdgcn_s_setprio(0);                                                      \
  }

  STAGE9(0)
  for (int t = 0; t < NTI - 1; ++t) {         // t = 0..11
    BAR();                                    // compute(t-1) done before overwriting its buf
    STAGE9(t + 1)
    VMC(4);                                   // tile t landed (t+1's 4 loads outstanding)
    BAR();
    asm volatile("" ::: "memory");
    COMPUTE9(t & 1)
  }
  BAR();
  VMC(0);
  BAR();
  asm volatile("" ::: "memory");
  COMPUTE9(0)                                 // t = 12 -> buf 0

#undef STAGE9
#undef COMPUTE9

  // ===== fused epilogue: dequant + relu -> LDS half-tile -> segmented sum -> agg atomics =====
  BAR();

  u16* tile = (u16*)lds;                        // [128][132] u16
  int* nseg = (int*)(lds + 33792);              // 128 ints
  float* sAl = (float*)(lds + 34304);           // 128 floats
  for (int i = tid; i < 128; i += 256) {
    nseg[i] = nsort[bm + i];
    sAl[i] = sA[bm + i];
  }
  __syncthreads();

  const int rq = (lane >> 4) * 4;
  const int cl = lane & 15;
#pragma unroll
  for (int j = 0; j < 4; ++j) {
    const int col16 = wn * 64 + j * 16 + cl;
    const float swn = sW[bn + col16];
    const float bj = bias[bn + col16];
#pragma unroll
    for (int i = 0; i < 4; ++i) {
      const int r0 = wm * 64 + i * 16 + rq;
#pragma unroll
      for (int q = 0; q < 4; ++q) {
        const int r = r0 + q;
        const float v = fmaf((float)acc[i][j][q], sAl[r] * swn, bj);
        tile[r * 132 + col16] = f2bf(v > 0.f ? v : 0.f);
      }
    }
  }
  __syncthreads();

  // 256 threads: col = tid&127, half = tid>>7 (rows 0-63 / 64-127)
  const int col = tid & 127;
  const int rbase = (tid >> 7) * 64;
  float s = 0.f;
  int cur = -1;
  for (int r = 0; r < 64; ++r) {
    const int nd = nseg[rbase + r];
    const float v = bf2f(tile[(rbase + r) * 132 + col]);
    if (nd != cur) {
      if (cur >= 0) atomicAdd(&agg[(size_t)cur * D_N + bn + col], s);
      s = 0.f;
      cur = nd;
    }
    if (nd >= 0) s += v;
  }
  if (cur >= 0) atomicAdd(&agg[(size_t)cur * D_N + bn + col], s);

#undef VMC
#undef BAR
}

// ---------------- GIN combine: h = (1+eps)*x + agg -> bf16 ----------------
__global__ void k_build_h(const float* __restrict__ x, const float* __restrict__ agg,
                          const float* __restrict__ epsp, u16* __restrict__ hbf) {
  int i = blockIdx.x * 256 + threadIdx.x;
  if (i >= U_N * D_N) return;
  float h = (1.f + epsp[0]) * x[i] + agg[i];
  hbf[i] = f2bf(h);
}

// ------- h1 GEMM: h1b = bf16(hbf @ W1^T), fused BN partial stats -------
__global__ __launch_bounds__(256)
void gemm_h1(const u16* __restrict__ A, const u16* __restrict__ B,
             u16* __restrict__ h1b, float* __restrict__ ssum, float* __restrict__ ssq) {
  __shared__ u16 As[128 * 64];
  __shared__ u16 Bs[128 * 64];
  const int bm = (blockIdx.x / 6) * 128;
  const int bn = (blockIdx.x % 6) * 128;
  const int t = threadIdx.x;
  const int wave = t >> 6, lane = t & 63;
  const int wr = (wave & 1) * 64, wc = (wave >> 1) * 64;
  const int srow = lane >> 3, scol = (lane & 7) * 8;
  const int rl = lane & 15, kl = (lane >> 4) * 8;
  f32x4 acc[4][4] = {};
  for (int k0 = 0; k0 < D_N; k0 += 64) {
#pragma unroll
    for (int q = 0; q < 4; q++) {
      const int c = wave * 4 + q;
      const int row = c * 8 + srow;
      gload16(A + (size_t)(bm + row) * D_N + k0 + scol, As + c * 512);
      gload16(B + (size_t)(bn + row) * D_N + k0 + scol, Bs + c * 512);
    }
    __syncthreads();
#pragma unroll
    for (int ks = 0; ks < 2; ks++) {
      s16x8 af[4], bfr[4];
#pragma unroll
      for (int i = 0; i < 4; i++) af[i] = *(const s16x8*)&As[(wr + i * 16 + rl) * 64 + ks * 32 + kl];
#pragma unroll
      for (int j = 0; j < 4; j++) bfr[j] = *(const s16x8*)&Bs[(wc + j * 16 + rl) * 64 + ks * 32 + kl];
#pragma unroll
      for (int i = 0; i < 4; i++)
#pragma unroll
        for (int j = 0; j < 4; j++)
          acc[i][j] = __builtin_amdgcn_mfma_f32_16x16x32_bf16(af[i], bfr[j], acc[i][j], 0, 0, 0);
    }
    __syncthreads();
  }
  const int cl = lane & 15, rq = (lane >> 4) * 4;
#pragma unroll
  for (int j = 0; j < 4; j++) {
    const int n = bn + wc + j * 16 + cl;
    float cs = 0.f, cq = 0.f;
#pragma unroll
    for (int i = 0; i < 4; i++) {
      const int r = bm + wr + i * 16 + rq;
#pragma unroll
      for (int q = 0; q < 4; q++) {
        const float v = acc[i][j][q];
        cs += v; cq += v * v;
        h1b[(size_t)(r + q) * D_N + n] = f2bf(v);
      }
    }
    cs += __shfl_xor(cs, 16); cq += __shfl_xor(cq, 16);
    cs += __shfl_xor(cs, 32); cq += __shfl_xor(cq, 32);
    if (lane < 16) { atomicAdd(&ssum[n], cs); atomicAdd(&ssq[n], cq); }
  }
}

// ---------------- generic bf16 GEMM, C f32 [M][N], K%64==0 ----------------
__global__ __launch_bounds__(256)
void gemm_bf16_g(const u16* __restrict__ A, const u16* __restrict__ B,
                 float* __restrict__ C, int ntn, int K) {
  __shared__ u16 As[128 * 64];
  __shared__ u16 Bs[128 * 64];
  const int bm = (blockIdx.x / ntn) * 128;
  const int bn = (blockIdx.x % ntn) * 128;
  const int t = threadIdx.x;
  const int wave = t >> 6, lane = t & 63;
  const int wr = (wave & 1) * 64, wc = (wave >> 1) * 64;
  const int srow = lane >> 3, scol = (lane & 7) * 8;
  const int rl = lane & 15, kl = (lane >> 4) * 8;
  const int N = ntn * 128;
  f32x4 acc[4][4] = {};
  for (int k0 = 0; k0 < K; k0 += 64) {
#pragma unroll
    for (int q = 0; q < 4; q++) {
      const int c = wave * 4 + q;
      const int row = c * 8 + srow;
      gload16(A + (size_t)(bm + row) * K + k0 + scol, As + c * 512);
      gload16(B + (size_t)(bn + row) * K + k0 + scol, Bs + c * 512);
    }
    __syncthreads();
#pragma unroll
    for (int ks = 0; ks < 2; ks++) {
      s16x8 af[4], bfr[4];
#pragma unroll
      for (int i = 0; i < 4; i++) af[i] = *(const s16x8*)&As[(wr + i * 16 + rl) * 64 + ks * 32 + kl];
#pragma unroll
      for (int j = 0; j < 4; j++) bfr[j] = *(const s16x8*)&Bs[(wc + j * 16 + rl) * 64 + ks * 32 + kl];
#pragma unroll
      for (int i = 0; i < 4; i++)
#pragma unroll
        for (int j = 0; j < 4; j++)
          acc[i][j] = __builtin_amdgcn_mfma_f32_16x16x32_bf16(af[i], bfr[j], acc[i][j], 0, 0, 0);
    }
    __syncthreads();
  }
  const int cl = lane & 15, rq = (lane >> 4) * 4;
#pragma unroll
  for (int i = 0; i < 4; i++)
#pragma unroll
    for (int j = 0; j < 4; j++) {
      const int n = bn + wc + j * 16 + cl;
      const int r = bm + wr + i * 16 + rq;
#pragma unroll
      for (int q = 0; q < 4; q++)
        C[(size_t)(r + q) * N + n] = acc[i][j][q];
    }
}

// ---------------- BN ----------------
__global__ void k_bnfinal(const float* __restrict__ ssum, const float* __restrict__ ssq,
                          const float* __restrict__ gamma, const float* __restrict__ beta,
                          float* __restrict__ scale, float* __restrict__ shift) {
  int c = blockIdx.x * 256 + threadIdx.x;
  if (c >= D_N) return;
  double mean = (double)ssum[c] / (double)U_N;
  double var = (double)ssq[c] / (double)U_N - mean * mean;
  float sc = (float)((double)gamma[c] / sqrt(var + (double)BN_EPS));
  scale[c] = sc;
  shift[c] = beta[c] - (float)mean * sc;
}

__global__ void k_bnapply(const u16* __restrict__ h1b, const float* __restrict__ scale,
                          const float* __restrict__ shift, u16* __restrict__ h2) {
  int i = blockIdx.x * 256 + threadIdx.x;
  if (i >= U_N * D_N) return;
  int c = i % D_N;
  float v = bf2f(h1b[i]) * scale[c] + shift[c];
  h2[i] = f2bf(v > 0.f ? v : 0.f);
}

extern "C" void kernel_launch(void* const* d_in, const int* in_sizes, int n_in,
                              void* d_out, int out_size, void* d_ws, size_t ws_size,
                              hipStream_t stream) {
  const float* x     = (const float*)d_in[0];
  const int*   uniq  = (const int*)d_in[1];
  const int*   srcg  = (const int*)d_in[2];
  const float* tgt   = (const float*)d_in[3];
  const float* edg   = (const float*)d_in[4];
  const float* Wedge = (const float*)d_in[5];
  const float* bedge = (const float*)d_in[6];
  const float* W1    = (const float*)d_in[7];
  const float* W2    = (const float*)d_in[8];
  const float* gamma = (const float*)d_in[9];
  const float* beta  = (const float*)d_in[10];
  const float* epsp  = (const float*)d_in[11];
  float* out = (float*)d_out;
  char* ws = (char*)d_ws;

  char*  Aq    = (char*) (ws + 0);             // 166,453,248 (M_PAD x 832)
  float* agg   = (float*)(ws + 166454272ull);  // 25,165,824
  u16*   h1b   = (u16*)  (ws + 191620096ull);  // 12,582,912
  u16*   hbf   = (u16*)  (ws + 204203008ull);  // 12,582,912
  u16*   h2b   = (u16*)  (ws + 216785920ull);  // 12,582,912
  char*  Wq    = (char*) (ws + 229368832ull);  // 638,976
  u16*   w1b   = (u16*)  (ws + 230007808ull);  // 1,179,648
  u16*   w2b   = (u16*)  (ws + 231187456ull);  // 1,179,648
  float* sA    = (float*)(ws + 232367104ull);  // 800,768
  float* sW    = (float*)(ws + 233167872ull);  // 4,096
  int*   lidx  = (int*)  (ws + 233171968ull);  // 800,000
  int*   eord  = (int*)  (ws + 233971968ull);  // 800,000
  int*   nsort = (int*)  (ws + 234771968ull);  // 800,768
  int*   counts= (int*)  (ws + 235572736ull);  // 32,768
  int*   cursor= (int*)  (ws + 235605504ull);  // 32,768
  int*   starts= (int*)  (ws + 235638272ull);  // 33,024
  float* ssum  = (float*)(ws + 235671296ull);  // 3,072
  float* ssq   = (float*)(ws + 235674368ull);
  float* scale = (float*)(ws + 235677440ull);
  float* shift = (float*)(ws + 235680512ull);

  hipMemsetAsync(counts, 0, 65536, stream);                 // counts + cursor
  hipMemsetAsync(ssum, 0, 2 * D_N * 4, stream);             // ssum + ssq
  hipMemsetAsync(agg, 0, (size_t)U_N * D_N * 4, stream);    // agg zeros
  hipMemsetAsync(nsort + E_N, 0xFF, (M_PAD - E_N) * 4, stream);  // pad rows -> -1

  k_convw_q8<<<D_N / 4, 256, 0, stream>>>(Wedge, Wq, sW);
  k_conv_w2<<<(2 * D_N * D_N + 255) / 256, 256, 0, stream>>>(W1, W2, w1b, w2b);

  k_lh<<<(E_N + 255) / 256, 256, 0, stream>>>(uniq, srcg, lidx, counts);
  k_scan<<<1, 1024, 0, stream>>>(counts, starts);
  k_scatter<<<(E_N + 255) / 256, 256, 0, stream>>>(lidx, starts, cursor, eord, nsort);

  k_pack_q8<<<E_N / 4, 256, 0, stream>>>(tgt, edg, eord, Aq, sA);

  // 1563 M-tiles x 6 N-tiles, 256 threads, 4 blocks/CU
  gemm_edge9<<<NMT * 6, 256, 0, stream>>>(Aq, Wq, sA, sW, bedge, nsort, agg);

  k_build_h<<<(U_N * D_N + 255) / 256, 256, 0, stream>>>(x, agg, epsp, hbf);

  gemm_h1<<<(U_N / 128) * 6, 256, 0, stream>>>(hbf, w1b, h1b, ssum, ssq);

  k_bnfinal<<<3, 256, 0, stream>>>(ssum, ssq, gamma, beta, scale, shift);
  k_bnapply<<<(U_N * D_N + 255) / 256, 256, 0, stream>>>(h1b, scale, shift, h2b);

  gemm_bf16_g<<<(U_N / 128) * 6, 256, 0, stream>>>(h2b, w2b, out, 6, D_N);
}